// Round 13
// baseline (287.831 us; speedup 1.0000x reference)
//
#include <hip/hip_runtime.h>
#include <hip/hip_bf16.h>

#define NL 2
#define NH 8
#define DKk 32
#define DVv 32
#define DFF 512
#define DD 256
#define BB 2
#define SS 2048
#define MROWS (BB*SS)            // 4096
#define LN_EPS 1e-14f
#define L2E 1.4426950408889634f
#define SOFT_SHIFT_L2E (50.0f*L2E)   // fixed softmax shift, in log2 units

typedef __hip_bfloat16 bf16;
typedef unsigned short us;
typedef short bf16x8 __attribute__((ext_vector_type(8)));   // 8 bf16 = 4 VGPRs
typedef float f32x4  __attribute__((ext_vector_type(4)));
typedef unsigned short us4 __attribute__((ext_vector_type(4)));

// ---- workspace layout (floats) ----
#define O_XF   256
#define O_QB   (O_XF+1048576)      // QH (1048576 us) + QL (1048576 us) frag-major
#define O_KH   (O_QB+1048576)
#define O_KL   (O_KH+524288)
#define O_VT   (O_KL+524288)
#define O_XH   (O_VT+524288)       // x pre-split hi (1048576 us)
#define O_XL   (O_XH+524288)       // x pre-split lo
#define O_OP   (O_XL+524288)       // 2097152: key-split x2 partial O (fh aliases)
#define O_ML   (O_OP+2097152)      // 65536: key-split l (m is constant)
#define O_MASK (O_ML+65536)
#define O_B1   (O_MASK+4096)
#define O_B2   (O_B1+1024)
#define O_GM   (O_B2+512)
#define O_BT   (O_GM+4)
#define O_PREP (O_BT+4)
// conv segments: x | mask | b1 | b2 | gamma | beta (weights prep'd from raw inputs)
#define CONV_TOTAL (1048576+4096+1024+512+4+4)
#define CONV_BLOCKS ((CONV_TOTAL+255)/256)
#define PREP_BLOCKS 512
// prep region offsets in ushorts (relative to (us*)(ws+O_PREP))
#define PQH 0u
#define PQL 393216u
#define POH 786432u
#define POL 917504u
#define P1H 1048576u
#define P1L 1310720u
#define P2H 1572864u
#define P2L 1835008u

__device__ __forceinline__ float us2f(us u){
  unsigned int v = ((unsigned int)u) << 16; float f;
  __builtin_memcpy(&f, &v, 4); return f;
}
__device__ __forceinline__ us f2bf_rne(float f){
  unsigned int b = __float_as_uint(f);
  b += 0x7FFFu + ((b>>16)&1u);
  return (us)(b>>16);
}

#if __has_builtin(__builtin_amdgcn_exp2f)
#define EXP2F(x) __builtin_amdgcn_exp2f(x)
#else
#define EXP2F(x) exp2f(x)
#endif

#if __has_builtin(__builtin_amdgcn_cvt_pk_bf16_f32)
typedef __bf16 bf16x2_t __attribute__((ext_vector_type(2)));
__device__ __forceinline__ int pack_bf16(float a, float b){
  bf16x2_t r = __builtin_amdgcn_cvt_pk_bf16_f32(a, b);
  int i; __builtin_memcpy(&i, &r, 4); return i;
}
#else
__device__ __forceinline__ int pack_bf16(float a, float b){
  int b0 = __float_as_int(a) + 0x8000;
  int b1 = __float_as_int(b) + 0x8000;
  return (b1 & 0xFFFF0000) | ((int)((unsigned)b0 >> 16));
}
#endif

// Async global->LDS 16B copy (lane-linear layouts only).
__device__ __forceinline__ void gl_lds16(const us* g, us* l){
  __builtin_amdgcn_global_load_lds(
    (const __attribute__((address_space(1))) unsigned int*)g,
    (__attribute__((address_space(3))) unsigned int*)l, 16, 0, 0);
}

// x pre-split frag-major index for element (row, col), K=256 tiling.
__device__ __forceinline__ size_t xhl_idx(int row, int col){
  int rt = row>>6, rg = (row>>4)&3, L15 = row&15;
  int kc = col>>5, Q = (col>>3)&3, j = col&7;
  return ((size_t)(rt*8+kc))*2048 + rg*512 + Q*128 + L15*8 + j;
}

// Detect whether inputs are bf16 (flag=0) or fp32 (flag=1).
__global__ void detect_kernel(const us* __restrict__ x, int n, int* __restrict__ flagp){
  __shared__ int bad;
  if(threadIdx.x==0) bad = 0;
  __syncthreads();
  int lim = n < 4096 ? n : 4096;
  int mybad = 0;
  for(int i=threadIdx.x; i<lim; i+=256){
    float f = us2f(x[i]);
    if(!(fabsf(f) < 1e3f)) mybad = 1;
  }
  if(mybad) atomicOr(&bad, 1);
  __syncthreads();
  if(threadIdx.x==0) *flagp = bad ? 1 : 0;
}

__device__ __forceinline__ float conv1(const void* src, size_t i, int flag){
  if(flag) return ((const float*)src)[i];
  return us2f(((const us*)src)[i]);
}

// Build fragment-major hi/lo bf16 B-operands reading RAW (flag-dtype) weights.
__device__ __forceinline__ void prep_b_raw(const void* W0, const void* W1v, const void* W2v,
                                           int baseoff, us* __restrict__ Bh, us* __restrict__ Bl,
                                           int Kd, int Nd, int qkv, int g, int flag)
{
  int total = (Kd/32)*(Nd/16)*64;
  if(g >= total) return;
  int lane = g & 63, fi = g >> 6;
  int ncN = Nd/16;
  int nc = fi % ncN, kc = fi / ncN;
  int Q = lane>>4, L15 = lane&15;
  int n = nc*16 + L15;
  const void* src;
  int off0, stride;
  if(qkv){
    int sec = n>>8, h = (n>>5)&7, kq = n&31;
    src = (sec==0)?W0:((sec==1)?W1v:W2v);
    off0 = baseoff + h*8192 + kq;
    stride = 32;
  } else {
    src = W0;
    off0 = baseoff + n;
    stride = Nd;
  }
  #pragma unroll
  for(int j=0;j<8;j++){
    int k = kc*32 + Q*8 + j;
    float v = conv1(src, (size_t)off0 + (size_t)k*stride, flag);
    us hb = f2bf_rne(v);
    Bh[(size_t)g*8 + j] = hb;
    Bl[(size_t)g*8 + j] = f2bf_rne(v - us2f(hb));
  }
}

// Fused: weight prep (blocks 0..511) + input conversion (remaining blocks).
// Conv: x -> xf + pre-split xhl; mask*log2e; b1/b2/gamma/beta -> fp32.
__global__ void conv_prep(const void* s0, const void* s1, const void* sWq, const void* sWk,
                          const void* sWv, const void* sWo, const void* sW1, const void* sb1,
                          const void* sW2, const void* sb2, const void* sgm, const void* sbt,
                          float* __restrict__ ws, const int* __restrict__ flagp)
{
  int flag = *flagp;
  int b = blockIdx.x;
  if(b < PREP_BLOCKS){
    int layer = b >> 8, lb = b & 255;
    us* prep = (us*)(ws + O_PREP);
    if(lb < 96){
      int g = lb*256 + threadIdx.x;
      prep_b_raw(sWq, sWk, sWv, layer*65536, prep+PQH+(size_t)layer*196608,
                 prep+PQL+(size_t)layer*196608, 256, 768, 1, g, flag);
    } else if(lb < 128){
      int g = (lb-96)*256 + threadIdx.x;
      prep_b_raw(sWo, nullptr, nullptr, layer*65536, prep+POH+(size_t)layer*65536,
                 prep+POL+(size_t)layer*65536, 256, 256, 0, g, flag);
    } else if(lb < 192){
      int g = (lb-128)*256 + threadIdx.x;
      prep_b_raw(sW1, nullptr, nullptr, layer*131072, prep+P1H+(size_t)layer*131072,
                 prep+P1L+(size_t)layer*131072, 256, 512, 0, g, flag);
    } else {
      int g = (lb-192)*256 + threadIdx.x;
      prep_b_raw(sW2, nullptr, nullptr, layer*131072, prep+P2H+(size_t)layer*131072,
                 prep+P2L+(size_t)layer*131072, 512, 256, 0, g, flag);
    }
    return;
  }
  int g = (b - PREP_BLOCKS)*256 + threadIdx.x;
  if(g < 1048576){
    float v = conv1(s0, g, flag);
    ws[O_XF+g] = v;
    us hb = f2bf_rne(v);
    us lb = f2bf_rne(v - us2f(hb));
    size_t xi = xhl_idx(g>>8, g&255);
    ((us*)(ws+O_XH))[xi] = hb;
    ((us*)(ws+O_XL))[xi] = lb;
    return;
  }
  g -= 1048576;
  if(g < 4096){ ws[O_MASK+g] = conv1(s1, g, flag)*L2E; return; }
  g -= 4096;
  if(g < 1024){ ws[O_B1+g] = conv1(sb1, g, flag); return; }
  g -= 1024;
  if(g < 512){ ws[O_B2+g] = conv1(sb2, g, flag); return; }
  g -= 512;
  if(g < 4){ ws[O_GM+g] = conv1(sgm, g, flag); return; }
  g -= 4;
  if(g < 4){ ws[O_BT+g] = conv1(sbt, g, flag); return; }
}

// Wide split-bf16 MFMA GEMM: tile 64x128, 4 waves (wave w = cols [w*32,+32)),
// A always pre-split frag-major (global_load_lds). 24 MFMAs / 12 b128 per wave/kc.
// MODE 0: QKV -> QH/QL, KH/KL, VT frag-major. MODE 2: relu(acc+bias) -> O.
template<int MODE>
__launch_bounds__(256)
__global__ void gemm_mfma_w(const us* __restrict__ Axh, const us* __restrict__ Axl,
                            const us* __restrict__ Bh, const us* __restrict__ Bl,
                            const float* __restrict__ bias,
                            float* __restrict__ O,
                            us* __restrict__ QH, us* __restrict__ QL,
                            us* __restrict__ KH, us* __restrict__ KL, us* __restrict__ VT,
                            int Ncols, int Kdim)
{
  __shared__ __align__(16) us Ah[2048], Al[2048];    // 64r x 32k frag-major
  __shared__ __align__(16) us Bhs[4096], Bls[4096];  // 32k x 128n frag-major
  const int t = threadIdx.x;
  const int w = t>>6, lane = t&63;
  const int Q = lane>>4, L15 = lane&15;
  const int row0 = blockIdx.x*64;
  const int nc0 = blockIdx.y*8;
  const int col0 = blockIdx.y*128;

  f32x4 acc[4][2];
  #pragma unroll
  for(int i=0;i<4;i++)
    #pragma unroll
    for(int j=0;j<2;j++) acc[i][j] = (f32x4){0.f,0.f,0.f,0.f};

  const int nKc = Kdim>>5;
  const int ncW = Ncols>>4;

  for(int kc=0; kc<nKc; kc++){
    {
      size_t abase = ((size_t)(blockIdx.x*nKc + kc))*2048;
      gl_lds16(&Axh[abase + (size_t)t*8], &Ah[t*8]);
      gl_lds16(&Axl[abase + (size_t)t*8], &Al[t*8]);
      #pragma unroll
      for(int ii=0; ii<2; ii++){
        int unit = w + ii*4;
        size_t gidx = ((size_t)(kc*ncW + nc0 + unit)*64 + lane)*8;
        gl_lds16(&Bh[gidx], &Bhs[unit*512 + lane*8]);
        gl_lds16(&Bl[gidx], &Bls[unit*512 + lane*8]);
      }
    }
    __syncthreads();

    bf16x8 aAh[4], aAl[4], bBh[2], bBl[2];
    #pragma unroll
    for(int rg=0;rg<4;rg++){
      aAh[rg] = *(const bf16x8*)&Ah[rg*512 + lane*8];
      aAl[rg] = *(const bf16x8*)&Al[rg*512 + lane*8];
    }
    #pragma unroll
    for(int cg2=0;cg2<2;cg2++){
      int unit = w*2 + cg2;
      bBh[cg2] = *(const bf16x8*)&Bhs[unit*512 + lane*8];
      bBl[cg2] = *(const bf16x8*)&Bls[unit*512 + lane*8];
    }
    #pragma unroll
    for(int rg=0;rg<4;rg++)
      #pragma unroll
      for(int cg2=0;cg2<2;cg2++){
        acc[rg][cg2] = __builtin_amdgcn_mfma_f32_16x16x32_bf16(aAl[rg], bBh[cg2], acc[rg][cg2], 0,0,0);
        acc[rg][cg2] = __builtin_amdgcn_mfma_f32_16x16x32_bf16(aAh[rg], bBl[cg2], acc[rg][cg2], 0,0,0);
        acc[rg][cg2] = __builtin_amdgcn_mfma_f32_16x16x32_bf16(aAh[rg], bBh[cg2], acc[rg][cg2], 0,0,0);
      }
    __syncthreads();
  }

  #pragma unroll
  for(int rg=0;rg<4;rg++)
    #pragma unroll
    for(int cg2=0;cg2<2;cg2++)
      #pragma unroll
      for(int r=0;r<4;r++){
        int row = row0 + rg*16 + Q*4 + r;
        int c   = col0 + w*32 + cg2*16 + L15;
        float va = acc[rg][cg2][r];
        if(MODE==0){
          int b_ = row>>11, s_ = row&2047;
          int sec = c>>8, h = (c>>5)&7, kq = c&31;
          int bh = b_*NH + h;
          size_t idx = ((size_t)(bh*128 + (s_>>4))*64 + (kq>>3)*16 + (s_&15))*8 + (kq&7);
          if(sec==0){
            us hb = f2bf_rne(va);
            QH[idx] = hb; QL[idx] = f2bf_rne(va - us2f(hb));
          } else if(sec==1){
            us hb = f2bf_rne(va);
            KH[idx] = hb; KL[idx] = f2bf_rne(va - us2f(hb));
          } else {
            size_t vidx = ((size_t)((bh*64 + (s_>>5))*2 + (kq>>4))*64 + ((s_&31)>>3)*16 + (kq&15))*8 + (s_&7);
            VT[vidx] = f2bf_rne(va);
          }
        } else {
          float v = va + bias[c];
          O[(size_t)row*Ncols + c] = v>0.f ? v : 0.f;
        }
      }
}

// 64x64 split-bf16 MFMA GEMM (kept for Wo and FFN2 where grid would shrink).
// ASRC 0: A fp32 convert-in-staging. ASRC 2: A = merged attention partials.
// MODE 1: res+acc. MODE 3: res+acc+bias.
template<int MODE, int ASRC>
__launch_bounds__(256)
__global__ void gemm_mfma(const float* __restrict__ A,
                          const float* __restrict__ OpartA, const float* __restrict__ MLA,
                          const us* __restrict__ Bh, const us* __restrict__ Bl,
                          const float* __restrict__ bias, const float* __restrict__ res,
                          float* __restrict__ O,
                          int Ncols, int Kdim)
{
  __shared__ __align__(16) us Ah[2048], Al[2048];
  __shared__ __align__(16) us Bhs[2048], Bls[2048];
  const int t = threadIdx.x;
  const int w = t>>6, lane = t&63;
  const int Q = lane>>4, L15 = lane&15;
  const int row0 = blockIdx.x*64;
  const int nc0 = blockIdx.y*4;
  const int col0 = blockIdx.y*64;

  f32x4 acc[2][2];
  #pragma unroll
  for(int i=0;i<2;i++)
    #pragma unroll
    for(int j=0;j<2;j++) acc[i][j] = (f32x4){0.f,0.f,0.f,0.f};

  const int r1 = t>>3;
  const int kl = (t&7)*4;
  const int Qc = kl>>3, j0 = kl&7;
  const int nKc = Kdim>>5;
  const int ncW = Ncols>>4;

  for(int kc=0; kc<nKc; kc++){
    {
      #pragma unroll
      for(int half=0; half<2; half++){
        int r = r1 + half*32;
        int rg = r>>4, L = r&15;
        float4 v;
        if(ASRC==2){
          int row = row0 + r;
          int b_ = row>>11, s_ = row&2047;
          size_t i0 = (size_t)(b_*8 + kc)*2048 + s_;     // h == kc (Kdim=256)
          float l = MLA[i0] + MLA[i0 + 32768];
          float inv = 1.f/l;
          float4 o0 = *(const float4*)&OpartA[i0*32 + kl];
          float4 o1 = *(const float4*)&OpartA[(i0+32768)*32 + kl];
          v.x=(o0.x+o1.x)*inv; v.y=(o0.y+o1.y)*inv;
          v.z=(o0.z+o1.z)*inv; v.w=(o0.w+o1.w)*inv;
        } else {
          v = *(const float4*)&A[(size_t)(row0+r)*Kdim + kc*32 + kl];
        }
        float f[4] = {v.x, v.y, v.z, v.w};
        us4 h4, l4;
        #pragma unroll
        for(int j=0;j<4;j++){
          us hb = f2bf_rne(f[j]);
          h4[j] = hb; l4[j] = f2bf_rne(f[j] - us2f(hb));
        }
        int off = (rg*4+Qc)*128 + L*8 + j0;
        *(us4*)&Ah[off] = h4;
        *(us4*)&Al[off] = l4;
      }
    }
    {
      size_t gidx = ((size_t)(kc*ncW + nc0 + w)*64 + lane)*8;
      gl_lds16(&Bh[gidx], &Bhs[t*8]);
      gl_lds16(&Bl[gidx], &Bls[t*8]);
    }
    __syncthreads();

    bf16x8 aAh[2], aAl[2], bBh[2], bBl[2];
    #pragma unroll
    for(int rg2=0;rg2<2;rg2++){
      int rg = (w&1)*2 + rg2;
      aAh[rg2] = *(const bf16x8*)&Ah[rg*512 + lane*8];
      aAl[rg2] = *(const bf16x8*)&Al[rg*512 + lane*8];
    }
    #pragma unroll
    for(int cg2=0;cg2<2;cg2++){
      int nc = (w>>1)*2 + cg2;
      bBh[cg2] = *(const bf16x8*)&Bhs[nc*512 + lane*8];
      bBl[cg2] = *(const bf16x8*)&Bls[nc*512 + lane*8];
    }
    #pragma unroll
    for(int rg2=0;rg2<2;rg2++)
      #pragma unroll
      for(int cg2=0;cg2<2;cg2++){
        acc[rg2][cg2] = __builtin_amdgcn_mfma_f32_16x16x32_bf16(aAl[rg2], bBh[cg2], acc[rg2][cg2], 0,0,0);
        acc[rg2][cg2] = __builtin_amdgcn_mfma_f32_16x16x32_bf16(aAh[rg2], bBl[cg2], acc[rg2][cg2], 0,0,0);
        acc[rg2][cg2] = __builtin_amdgcn_mfma_f32_16x16x32_bf16(aAh[rg2], bBh[cg2], acc[rg2][cg2], 0,0,0);
      }
    __syncthreads();
  }

  #pragma unroll
  for(int rg2=0;rg2<2;rg2++)
    #pragma unroll
    for(int cg2=0;cg2<2;cg2++)
      #pragma unroll
      for(int r=0;r<4;r++){
        int row = row0 + (w&1)*32 + rg2*16 + Q*4 + r;
        int c   = col0 + (w>>1)*32 + cg2*16 + L15;
        float va = acc[rg2][cg2][r];
        if(MODE==1){
          O[(size_t)row*Ncols + c] = res[(size_t)row*Ncols + c] + va;
        } else {
          O[(size_t)row*Ncols + c] = res[(size_t)row*Ncols + c] + va + bias[c];
        }
      }
}

// MFMA flash attention v7 (unchanged from R12): exp2 softmax, cvt_pk pack,
// frag-major Q prologue, key-split x2, async LDS staging.
__launch_bounds__(256)
__global__ void attn_kernel(const us* __restrict__ QH, const us* __restrict__ QL,
                            const us* __restrict__ KH, const us* __restrict__ KL,
                            const us* __restrict__ VT,
                            const float* __restrict__ mask,
                            float* __restrict__ Opart, float* __restrict__ ML)
{
  __shared__ __align__(16) us Khs[4096], Kls[4096], Vts[4096];
  __shared__ __align__(16) float Msl[128];
  const int t = threadIdx.x;
  const int bh = blockIdx.x >> 6;
  const int qt = (blockIdx.x & 63) >> 1;
  const int ks = blockIdx.x & 1;
  const int b_ = bh >> 3;
  const int wv = t >> 6;
  const int lane = t & 63;
  const int Q = lane >> 4, L15 = lane & 15;
  const int q0 = qt*64 + wv*16;

  size_t qidx = ((size_t)(bh*128 + qt*4 + wv)*64 + lane)*8;
  const bf16x8 qh_v = *(const bf16x8*)&QH[qidx];
  const bf16x8 ql_v = *(const bf16x8*)&QL[qidx];

  const us* KHbh = KH + (size_t)bh*65536;
  const us* KLbh = KL + (size_t)bh*65536;
  const us* VTbh = VT + (size_t)bh*65536;

  f32x4 Oa0a = {0.f,0.f,0.f,0.f}, Oa0b = {0.f,0.f,0.f,0.f};
  f32x4 Oa1a = {0.f,0.f,0.f,0.f}, Oa1b = {0.f,0.f,0.f,0.f};
  float lacc = 0.f;

  const int kend = ks*1024 + 1024;
  for(int t0 = ks*1024; t0 < kend; t0 += 128){
    {
      size_t kbase = (size_t)(t0>>4)*512;
      size_t vbase = (size_t)(t0>>5)*1024;
      #pragma unroll
      for(int ii=0; ii<2; ii++){
        int s = t + ii*256;
        gl_lds16(&KHbh[kbase + (size_t)s*8], &Khs[s*8]);
        gl_lds16(&KLbh[kbase + (size_t)s*8], &Kls[s*8]);
        gl_lds16(&VTbh[vbase + (size_t)s*8], &Vts[s*8]);
      }
      if(t < 128) Msl[t] = mask[b_*SS + t0 + t];   // mask pre-scaled by log2e
    }
    __syncthreads();

    // QK^T -> S^T (3 MFMAs per 16-key tile, 8 tiles)
    f32x4 St[8];
    const f32x4 zz = {0.f,0.f,0.f,0.f};
    #pragma unroll
    for(int kt=0;kt<8;kt++){
      bf16x8 aKh = *(const bf16x8*)&Khs[kt*512 + lane*8];
      bf16x8 aKl = *(const bf16x8*)&Kls[kt*512 + lane*8];
      f32x4 a = __builtin_amdgcn_mfma_f32_16x16x32_bf16(aKl, qh_v, zz, 0,0,0);
      a = __builtin_amdgcn_mfma_f32_16x16x32_bf16(aKh, ql_v, a, 0,0,0);
      a = __builtin_amdgcn_mfma_f32_16x16x32_bf16(aKh, qh_v, a, 0,0,0);
      St[kt] = a;
    }

    // fixed-shift softmax in log2 space: p = exp2(mv_l2e * S - 50*l2e)
    float lsum = 0.f;
    #pragma unroll
    for(int kt=0;kt<8;kt++){
      float4 mv = *(const float4*)&Msl[kt*16 + Q*4];
      float mvr[4] = {mv.x, mv.y, mv.z, mv.w};
      #pragma unroll
      for(int r=0;r<4;r++){
        float p = EXP2F(fmaf(mvr[r], St[kt][r], -SOFT_SHIFT_L2E));
        St[kt][r] = p;
        lsum += p;
      }
    }
    lacc += lsum;

    // pack P -> bf16 pairs
    int pk[8][2];
    #pragma unroll
    for(int kt=0;kt<8;kt++){
      pk[kt][0] = pack_bf16(St[kt][0], St[kt][1]);
      pk[kt][1] = pack_bf16(St[kt][2], St[kt][3]);
    }

    // PV: O^T += V^T · P^T (chunks 0,1 -> a; 2,3 -> b)
    #pragma unroll
    for(int c=0;c<4;c++){
      union { int i[4]; bf16x8 v; } bu;
      #pragma unroll
      for(int d=0;d<4;d++){
        int srcl = (((Q&1)*2 + (d>>1))<<4) | L15;
        int vlo = __shfl(pk[2*c  ][d&1], srcl, 64);
        int vhi = __shfl(pk[2*c+1][d&1], srcl, 64);
        bu.i[d] = (Q & 2) ? vhi : vlo;
      }
      bf16x8 aV0 = *(const bf16x8*)&Vts[(c*2+0)*512 + lane*8];
      bf16x8 aV1 = *(const bf16x8*)&Vts[(c*2+1)*512 + lane*8];
      if(c < 2){
        Oa0a = __builtin_amdgcn_mfma_f32_16x16x32_bf16(aV0, bu.v, Oa0a, 0,0,0);
        Oa1a = __builtin_amdgcn_mfma_f32_16x16x32_bf16(aV1, bu.v, Oa1a, 0,0,0);
      } else {
        Oa0b = __builtin_amdgcn_mfma_f32_16x16x32_bf16(aV0, bu.v, Oa0b, 0,0,0);
        Oa1b = __builtin_amdgcn_mfma_f32_16x16x32_bf16(aV1, bu.v, Oa1b, 0,0,0);
      }
    }
    __syncthreads();
  }

  f32x4 Oa0 = Oa0a + Oa0b;
  f32x4 Oa1 = Oa1a + Oa1b;
  lacc += __shfl_xor(lacc, 16);
  lacc += __shfl_xor(lacc, 32);

  float* opp = &Opart[((size_t)(ks*16+bh)*SS + q0 + L15)*32];
  #pragma unroll
  for(int r=0;r<4;r++){
    opp[Q*4+r]    = Oa0[r];
    opp[16+Q*4+r] = Oa1[r];
  }
  if(Q==0){
    ML[(size_t)(ks*16+bh)*SS + q0 + L15] = lacc;
  }
}

// LayerNorm over D=256, one row per block, in-place; shfl-based reduction.
// Also emits pre-split xhl and (optionally) the final output.
__launch_bounds__(256)
__global__ void ln_kernel(float* __restrict__ xf, const float* __restrict__ gamma,
                          const float* __restrict__ beta, int gi,
                          us* __restrict__ xh, us* __restrict__ xl,
                          void* __restrict__ out, int write_out,
                          const int* __restrict__ flagp)
{
  __shared__ float s1[4], s2[4];
  const int r = blockIdx.x;
  const int t = threadIdx.x;
  float v = xf[(size_t)r*DD + t];
  float sum = v, sumsq = v*v;
  #pragma unroll
  for(int off=1; off<64; off<<=1){
    sum   += __shfl_xor(sum, off);
    sumsq += __shfl_xor(sumsq, off);
  }
  if((t&63)==0){ s1[t>>6]=sum; s2[t>>6]=sumsq; }
  __syncthreads();
  float tot  = s1[0]+s1[1]+s1[2]+s1[3];
  float tot2 = s2[0]+s2[1]+s2[2]+s2[3];
  float mean = tot*(1.f/DD);
  float var  = tot2*(1.f/DD) - mean*mean;
  float g = gamma[gi], bb = beta[gi];
  float val = (v-mean)*rsqrtf(var+LN_EPS)*g + bb;
  xf[(size_t)r*DD + t] = val;
  us hb = f2bf_rne(val);
  us lb = f2bf_rne(val - us2f(hb));
  size_t xi = xhl_idx(r, t);
  xh[xi] = hb; xl[xi] = lb;
  if(write_out){
    if(*flagp) ((float*)out)[(size_t)r*DD + t] = val;
    else       ((bf16*)out)[(size_t)r*DD + t] = __float2bfloat16(val);
  }
}

extern "C" void kernel_launch(void* const* d_in, const int* in_sizes, int n_in,
                              void* d_out, int out_size, void* d_ws, size_t ws_size,
                              hipStream_t stream)
{
  float* ws = (float*)d_ws;
  int* flagp = (int*)d_ws;

  float* xf  = ws + O_XF;
  us* QHb = (us*)(ws + O_QB);
  us* QLb = QHb + 1048576;
  us* KH = (us*)(ws + O_KH);
  us* KL = (us*)(ws + O_KL);
  us* VT = (us*)(ws + O_VT);
  us* XH = (us*)(ws + O_XH);
  us* XL = (us*)(ws + O_XL);
  float* Opart = ws + O_OP;
  float* ML  = ws + O_ML;
  float* fh  = Opart;                   // FFN hidden aliases Opart (dead after Wo-GEMM)
  float* b1f = ws + O_B1;
  float* b2f_ = ws + O_B2;
  float* gmf = ws + O_GM;
  float* btf = ws + O_BT;
  us* prep = (us*)(ws + O_PREP);

  detect_kernel<<<1,256,0,stream>>>((const us*)d_in[0], in_sizes[0], flagp);
  conv_prep<<<PREP_BLOCKS+CONV_BLOCKS,256,0,stream>>>(
      d_in[0], d_in[1], d_in[2], d_in[3], d_in[4], d_in[5],
      d_in[6], d_in[7], d_in[8], d_in[9], d_in[10], d_in[11],
      ws, flagp);

  for(int i=0;i<NL;i++){
    const float* b1i = b1f + (size_t)i*DFF;
    const float* b2i = b2f_ + (size_t)i*DD;

    dim3 g0(64, 6);
    gemm_mfma_w<0><<<g0,256,0,stream>>>(XH, XL,
                                        prep+PQH+(size_t)i*196608, prep+PQL+(size_t)i*196608,
                                        nullptr, nullptr,
                                        QHb, QLb, KH, KL, VT, 768, 256);
    attn_kernel<<<1024,256,0,stream>>>(QHb, QLb, KH, KL, VT, ws + O_MASK, Opart, ML);
    dim3 g1(64, 4);
    gemm_mfma<1,2><<<g1,256,0,stream>>>(nullptr, Opart, ML,
                                        prep+POH+(size_t)i*65536, prep+POL+(size_t)i*65536,
                                        nullptr, xf, xf, 256, 256);
    ln_kernel<<<MROWS,256,0,stream>>>(xf, gmf, btf, 2*i, XH, XL, d_out, 0, flagp);
    dim3 g2(64, 4);
    gemm_mfma_w<2><<<g2,256,0,stream>>>(XH, XL,
                                        prep+P1H+(size_t)i*131072, prep+P1L+(size_t)i*131072,
                                        b1i, fh,
                                        nullptr, nullptr, nullptr, nullptr, nullptr, 512, 256);
    dim3 g3(64, 4);
    gemm_mfma<3,0><<<g3,256,0,stream>>>(fh, nullptr, nullptr,
                                        prep+P2H+(size_t)i*131072, prep+P2L+(size_t)i*131072,
                                        b2i, xf, xf, 256, 512);
    ln_kernel<<<MROWS,256,0,stream>>>(xf, gmf, btf, 2*i+1, XH, XL, d_out, (i==NL-1)?1:0, flagp);
  }
}

// Round 14
// 279.335 us; speedup vs baseline: 1.0304x; 1.0304x over previous
//
#include <hip/hip_runtime.h>
#include <hip/hip_bf16.h>

#define NL 2
#define NH 8
#define DKk 32
#define DVv 32
#define DFF 512
#define DD 256
#define BB 2
#define SS 2048
#define MROWS (BB*SS)            // 4096
#define LN_EPS 1e-14f
#define L2E 1.4426950408889634f
#define SOFT_SHIFT_L2E (50.0f*L2E)   // fixed softmax shift, in log2 units

typedef __hip_bfloat16 bf16;
typedef unsigned short us;
typedef short bf16x8 __attribute__((ext_vector_type(8)));   // 8 bf16 = 4 VGPRs
typedef float f32x4  __attribute__((ext_vector_type(4)));
typedef unsigned short us4 __attribute__((ext_vector_type(4)));

// ---- workspace layout (floats) ----
#define O_XF   256
#define O_QB   (O_XF+1048576)      // QH (1048576 us) + QL (1048576 us) frag-major
#define O_KH   (O_QB+1048576)
#define O_KL   (O_KH+524288)
#define O_VT   (O_KL+524288)
#define O_XH   (O_VT+524288)       // x pre-split hi (1048576 us)
#define O_XL   (O_XH+524288)       // x pre-split lo
#define O_OP   (O_XL+524288)       // 2097152: key-split x2 partial O (fh aliases)
#define O_ML   (O_OP+2097152)      // 65536: key-split l (m is constant)
#define O_MASK (O_ML+65536)
#define O_B1   (O_MASK+4096)
#define O_B2   (O_B1+1024)
#define O_GM   (O_B2+512)
#define O_BT   (O_GM+4)
#define O_PREP (O_BT+4)
// conv segments: x | mask | b1 | b2 | gamma | beta (weights prep'd from raw inputs)
#define CONV_TOTAL (1048576+4096+1024+512+4+4)
#define CONV_BLOCKS ((CONV_TOTAL+255)/256)
#define PREP_BLOCKS 512
// prep region offsets in ushorts (relative to (us*)(ws+O_PREP))
#define PQH 0u
#define PQL 393216u
#define POH 786432u
#define POL 917504u
#define P1H 1048576u
#define P1L 1310720u
#define P2H 1572864u
#define P2L 1835008u

__device__ __forceinline__ float us2f(us u){
  unsigned int v = ((unsigned int)u) << 16; float f;
  __builtin_memcpy(&f, &v, 4); return f;
}
__device__ __forceinline__ us f2bf_rne(float f){
  unsigned int b = __float_as_uint(f);
  b += 0x7FFFu + ((b>>16)&1u);
  return (us)(b>>16);
}

#if __has_builtin(__builtin_amdgcn_exp2f)
#define EXP2F(x) __builtin_amdgcn_exp2f(x)
#else
#define EXP2F(x) exp2f(x)
#endif

#if __has_builtin(__builtin_amdgcn_cvt_pk_bf16_f32)
typedef __bf16 bf16x2_t __attribute__((ext_vector_type(2)));
__device__ __forceinline__ int pack_bf16(float a, float b){
  bf16x2_t r = __builtin_amdgcn_cvt_pk_bf16_f32(a, b);
  int i; __builtin_memcpy(&i, &r, 4); return i;
}
#else
__device__ __forceinline__ int pack_bf16(float a, float b){
  int b0 = __float_as_int(a) + 0x8000;
  int b1 = __float_as_int(b) + 0x8000;
  return (b1 & 0xFFFF0000) | ((int)((unsigned)b0 >> 16));
}
#endif

// Async global->LDS 16B copy (lane-linear layouts only).
__device__ __forceinline__ void gl_lds16(const us* g, us* l){
  __builtin_amdgcn_global_load_lds(
    (const __attribute__((address_space(1))) unsigned int*)g,
    (__attribute__((address_space(3))) unsigned int*)l, 16, 0, 0);
}

// x pre-split frag-major index for element (row, col), K=256 tiling.
__device__ __forceinline__ size_t xhl_idx(int row, int col){
  int rt = row>>6, rg = (row>>4)&3, L15 = row&15;
  int kc = col>>5, Q = (col>>3)&3, j = col&7;
  return ((size_t)(rt*8+kc))*2048 + rg*512 + Q*128 + L15*8 + j;
}

// Detect whether inputs are bf16 (flag=0) or fp32 (flag=1).
__global__ void detect_kernel(const us* __restrict__ x, int n, int* __restrict__ flagp){
  __shared__ int bad;
  if(threadIdx.x==0) bad = 0;
  __syncthreads();
  int lim = n < 4096 ? n : 4096;
  int mybad = 0;
  for(int i=threadIdx.x; i<lim; i+=256){
    float f = us2f(x[i]);
    if(!(fabsf(f) < 1e3f)) mybad = 1;
  }
  if(mybad) atomicOr(&bad, 1);
  __syncthreads();
  if(threadIdx.x==0) *flagp = bad ? 1 : 0;
}

__device__ __forceinline__ float conv1(const void* src, size_t i, int flag){
  if(flag) return ((const float*)src)[i];
  return us2f(((const us*)src)[i]);
}

// Build fragment-major hi/lo bf16 B-operands reading RAW (flag-dtype) weights.
__device__ __forceinline__ void prep_b_raw(const void* W0, const void* W1v, const void* W2v,
                                           int baseoff, us* __restrict__ Bh, us* __restrict__ Bl,
                                           int Kd, int Nd, int qkv, int g, int flag)
{
  int total = (Kd/32)*(Nd/16)*64;
  if(g >= total) return;
  int lane = g & 63, fi = g >> 6;
  int ncN = Nd/16;
  int nc = fi % ncN, kc = fi / ncN;
  int Q = lane>>4, L15 = lane&15;
  int n = nc*16 + L15;
  const void* src;
  int off0, stride;
  if(qkv){
    int sec = n>>8, h = (n>>5)&7, kq = n&31;
    src = (sec==0)?W0:((sec==1)?W1v:W2v);
    off0 = baseoff + h*8192 + kq;
    stride = 32;
  } else {
    src = W0;
    off0 = baseoff + n;
    stride = Nd;
  }
  #pragma unroll
  for(int j=0;j<8;j++){
    int k = kc*32 + Q*8 + j;
    float v = conv1(src, (size_t)off0 + (size_t)k*stride, flag);
    us hb = f2bf_rne(v);
    Bh[(size_t)g*8 + j] = hb;
    Bl[(size_t)g*8 + j] = f2bf_rne(v - us2f(hb));
  }
}

// Fused: weight prep (blocks 0..511) + input conversion (remaining blocks).
__global__ void conv_prep(const void* s0, const void* s1, const void* sWq, const void* sWk,
                          const void* sWv, const void* sWo, const void* sW1, const void* sb1,
                          const void* sW2, const void* sb2, const void* sgm, const void* sbt,
                          float* __restrict__ ws, const int* __restrict__ flagp)
{
  int flag = *flagp;
  int b = blockIdx.x;
  if(b < PREP_BLOCKS){
    int layer = b >> 8, lb = b & 255;
    us* prep = (us*)(ws + O_PREP);
    if(lb < 96){
      int g = lb*256 + threadIdx.x;
      prep_b_raw(sWq, sWk, sWv, layer*65536, prep+PQH+(size_t)layer*196608,
                 prep+PQL+(size_t)layer*196608, 256, 768, 1, g, flag);
    } else if(lb < 128){
      int g = (lb-96)*256 + threadIdx.x;
      prep_b_raw(sWo, nullptr, nullptr, layer*65536, prep+POH+(size_t)layer*65536,
                 prep+POL+(size_t)layer*65536, 256, 256, 0, g, flag);
    } else if(lb < 192){
      int g = (lb-128)*256 + threadIdx.x;
      prep_b_raw(sW1, nullptr, nullptr, layer*131072, prep+P1H+(size_t)layer*131072,
                 prep+P1L+(size_t)layer*131072, 256, 512, 0, g, flag);
    } else {
      int g = (lb-192)*256 + threadIdx.x;
      prep_b_raw(sW2, nullptr, nullptr, layer*131072, prep+P2H+(size_t)layer*131072,
                 prep+P2L+(size_t)layer*131072, 512, 256, 0, g, flag);
    }
    return;
  }
  int g = (b - PREP_BLOCKS)*256 + threadIdx.x;
  if(g < 1048576){
    float v = conv1(s0, g, flag);
    ws[O_XF+g] = v;
    us hb = f2bf_rne(v);
    us lb = f2bf_rne(v - us2f(hb));
    size_t xi = xhl_idx(g>>8, g&255);
    ((us*)(ws+O_XH))[xi] = hb;
    ((us*)(ws+O_XL))[xi] = lb;
    return;
  }
  g -= 1048576;
  if(g < 4096){ ws[O_MASK+g] = conv1(s1, g, flag)*L2E; return; }
  g -= 4096;
  if(g < 1024){ ws[O_B1+g] = conv1(sb1, g, flag); return; }
  g -= 1024;
  if(g < 512){ ws[O_B2+g] = conv1(sb2, g, flag); return; }
  g -= 512;
  if(g < 4){ ws[O_GM+g] = conv1(sgm, g, flag); return; }
  g -= 4;
  if(g < 4){ ws[O_BT+g] = conv1(sbt, g, flag); return; }
}

// Split-bf16 MFMA GEMM (R12 config: 64x64 tile, 4 waves, 3 MFMAs/frag/K32).
// ASRC 0: A fp32, convert in staging. ASRC 1: A pre-split (global_load_lds).
// ASRC 2: A = merged attention out (sum of 2 key-split partials / sum l).
// MODE 0: QKV -> QH/QL, KH/KL, VT frag-major bf16.
// MODE 1: res+acc. MODE 2: relu(acc+bias). MODE 3: res+acc+bias.
template<int MODE, int ASRC>
__launch_bounds__(256)
__global__ void gemm_mfma(const float* __restrict__ A,
                          const us* __restrict__ Axh, const us* __restrict__ Axl,
                          const float* __restrict__ OpartA, const float* __restrict__ MLA,
                          const us* __restrict__ Bh, const us* __restrict__ Bl,
                          const float* __restrict__ bias, const float* __restrict__ res,
                          float* __restrict__ O,
                          us* __restrict__ QH, us* __restrict__ QL,
                          us* __restrict__ KH, us* __restrict__ KL, us* __restrict__ VT,
                          int Ncols, int Kdim)
{
  __shared__ __align__(16) us Ah[2048], Al[2048];
  __shared__ __align__(16) us Bhs[2048], Bls[2048];
  const int t = threadIdx.x;
  const int w = t>>6, lane = t&63;
  const int Q = lane>>4, L15 = lane&15;
  const int row0 = blockIdx.x*64;
  const int nc0 = blockIdx.y*4;
  const int col0 = blockIdx.y*64;

  f32x4 acc[2][2];
  #pragma unroll
  for(int i=0;i<2;i++)
    #pragma unroll
    for(int j=0;j<2;j++) acc[i][j] = (f32x4){0.f,0.f,0.f,0.f};

  const int r1 = t>>3;
  const int kl = (t&7)*4;
  const int Qc = kl>>3, j0 = kl&7;
  const int nKc = Kdim>>5;
  const int ncW = Ncols>>4;

  for(int kc=0; kc<nKc; kc++){
    if(ASRC==1){
      size_t abase = ((size_t)(blockIdx.x*nKc + kc))*2048;
      gl_lds16(&Axh[abase + (size_t)t*8], &Ah[t*8]);
      gl_lds16(&Axl[abase + (size_t)t*8], &Al[t*8]);
    } else {
      #pragma unroll
      for(int half=0; half<2; half++){
        int r = r1 + half*32;
        int rg = r>>4, L = r&15;
        float4 v;
        if(ASRC==2){
          int row = row0 + r;
          int b_ = row>>11, s_ = row&2047;
          size_t i0 = (size_t)(b_*8 + kc)*2048 + s_;     // h == kc (Kdim=256)
          float l = MLA[i0] + MLA[i0 + 32768];
          float inv = 1.f/l;
          float4 o0 = *(const float4*)&OpartA[i0*32 + kl];
          float4 o1 = *(const float4*)&OpartA[(i0+32768)*32 + kl];
          v.x=(o0.x+o1.x)*inv; v.y=(o0.y+o1.y)*inv;
          v.z=(o0.z+o1.z)*inv; v.w=(o0.w+o1.w)*inv;
        } else {
          v = *(const float4*)&A[(size_t)(row0+r)*Kdim + kc*32 + kl];
        }
        float f[4] = {v.x, v.y, v.z, v.w};
        us4 h4, l4;
        #pragma unroll
        for(int j=0;j<4;j++){
          us hb = f2bf_rne(f[j]);
          h4[j] = hb; l4[j] = f2bf_rne(f[j] - us2f(hb));
        }
        int off = (rg*4+Qc)*128 + L*8 + j0;
        *(us4*)&Ah[off] = h4;
        *(us4*)&Al[off] = l4;
      }
    }
    {
      size_t gidx = ((size_t)(kc*ncW + nc0 + w)*64 + lane)*8;
      gl_lds16(&Bh[gidx], &Bhs[t*8]);
      gl_lds16(&Bl[gidx], &Bls[t*8]);
    }
    __syncthreads();

    bf16x8 aAh[2], aAl[2], bBh[2], bBl[2];
    #pragma unroll
    for(int rg2=0;rg2<2;rg2++){
      int rg = (w&1)*2 + rg2;
      aAh[rg2] = *(const bf16x8*)&Ah[rg*512 + lane*8];
      aAl[rg2] = *(const bf16x8*)&Al[rg*512 + lane*8];
    }
    #pragma unroll
    for(int cg2=0;cg2<2;cg2++){
      int nc = (w>>1)*2 + cg2;
      bBh[cg2] = *(const bf16x8*)&Bhs[nc*512 + lane*8];
      bBl[cg2] = *(const bf16x8*)&Bls[nc*512 + lane*8];
    }
    #pragma unroll
    for(int rg2=0;rg2<2;rg2++)
      #pragma unroll
      for(int cg2=0;cg2<2;cg2++){
        acc[rg2][cg2] = __builtin_amdgcn_mfma_f32_16x16x32_bf16(aAl[rg2], bBh[cg2], acc[rg2][cg2], 0,0,0);
        acc[rg2][cg2] = __builtin_amdgcn_mfma_f32_16x16x32_bf16(aAh[rg2], bBl[cg2], acc[rg2][cg2], 0,0,0);
        acc[rg2][cg2] = __builtin_amdgcn_mfma_f32_16x16x32_bf16(aAh[rg2], bBh[cg2], acc[rg2][cg2], 0,0,0);
      }
    __syncthreads();
  }

  #pragma unroll
  for(int rg2=0;rg2<2;rg2++)
    #pragma unroll
    for(int cg2=0;cg2<2;cg2++)
      #pragma unroll
      for(int r=0;r<4;r++){
        int row = row0 + (w&1)*32 + rg2*16 + Q*4 + r;
        int c   = col0 + (w>>1)*32 + cg2*16 + L15;
        float va = acc[rg2][cg2][r];
        if(MODE==0){
          int b_ = row>>11, s_ = row&2047;
          int sec = c>>8, h = (c>>5)&7, kq = c&31;
          int bh = b_*NH + h;
          size_t idx = ((size_t)(bh*128 + (s_>>4))*64 + (kq>>3)*16 + (s_&15))*8 + (kq&7);
          if(sec==0){
            us hb = f2bf_rne(va);
            QH[idx] = hb; QL[idx] = f2bf_rne(va - us2f(hb));
          } else if(sec==1){
            us hb = f2bf_rne(va);
            KH[idx] = hb; KL[idx] = f2bf_rne(va - us2f(hb));
          } else {
            size_t vidx = ((size_t)((bh*64 + (s_>>5))*2 + (kq>>4))*64 + ((s_&31)>>3)*16 + (kq&15))*8 + (s_&7);
            VT[vidx] = f2bf_rne(va);
          }
        } else if(MODE==1){
          O[(size_t)row*Ncols + c] = res[(size_t)row*Ncols + c] + va;
        } else if(MODE==2){
          float v = va + bias[c];
          O[(size_t)row*Ncols + c] = v>0.f ? v : 0.f;
        } else {
          O[(size_t)row*Ncols + c] = res[(size_t)row*Ncols + c] + va + bias[c];
        }
      }
}

// MFMA flash attention v7 (R12): exp2 softmax, cvt_pk pack, frag-major Q,
// key-split x2, async LDS staging.
__launch_bounds__(256)
__global__ void attn_kernel(const us* __restrict__ QH, const us* __restrict__ QL,
                            const us* __restrict__ KH, const us* __restrict__ KL,
                            const us* __restrict__ VT,
                            const float* __restrict__ mask,
                            float* __restrict__ Opart, float* __restrict__ ML)
{
  __shared__ __align__(16) us Khs[4096], Kls[4096], Vts[4096];
  __shared__ __align__(16) float Msl[128];
  const int t = threadIdx.x;
  const int bh = blockIdx.x >> 6;
  const int qt = (blockIdx.x & 63) >> 1;
  const int ks = blockIdx.x & 1;
  const int b_ = bh >> 3;
  const int wv = t >> 6;
  const int lane = t & 63;
  const int Q = lane >> 4, L15 = lane & 15;
  const int q0 = qt*64 + wv*16;

  size_t qidx = ((size_t)(bh*128 + qt*4 + wv)*64 + lane)*8;
  const bf16x8 qh_v = *(const bf16x8*)&QH[qidx];
  const bf16x8 ql_v = *(const bf16x8*)&QL[qidx];

  const us* KHbh = KH + (size_t)bh*65536;
  const us* KLbh = KL + (size_t)bh*65536;
  const us* VTbh = VT + (size_t)bh*65536;

  f32x4 Oa0a = {0.f,0.f,0.f,0.f}, Oa0b = {0.f,0.f,0.f,0.f};
  f32x4 Oa1a = {0.f,0.f,0.f,0.f}, Oa1b = {0.f,0.f,0.f,0.f};
  float lacc = 0.f;

  const int kend = ks*1024 + 1024;
  for(int t0 = ks*1024; t0 < kend; t0 += 128){
    {
      size_t kbase = (size_t)(t0>>4)*512;
      size_t vbase = (size_t)(t0>>5)*1024;
      #pragma unroll
      for(int ii=0; ii<2; ii++){
        int s = t + ii*256;
        gl_lds16(&KHbh[kbase + (size_t)s*8], &Khs[s*8]);
        gl_lds16(&KLbh[kbase + (size_t)s*8], &Kls[s*8]);
        gl_lds16(&VTbh[vbase + (size_t)s*8], &Vts[s*8]);
      }
      if(t < 128) Msl[t] = mask[b_*SS + t0 + t];   // mask pre-scaled by log2e
    }
    __syncthreads();

    // QK^T -> S^T (3 MFMAs per 16-key tile, 8 tiles)
    f32x4 St[8];
    const f32x4 zz = {0.f,0.f,0.f,0.f};
    #pragma unroll
    for(int kt=0;kt<8;kt++){
      bf16x8 aKh = *(const bf16x8*)&Khs[kt*512 + lane*8];
      bf16x8 aKl = *(const bf16x8*)&Kls[kt*512 + lane*8];
      f32x4 a = __builtin_amdgcn_mfma_f32_16x16x32_bf16(aKl, qh_v, zz, 0,0,0);
      a = __builtin_amdgcn_mfma_f32_16x16x32_bf16(aKh, ql_v, a, 0,0,0);
      a = __builtin_amdgcn_mfma_f32_16x16x32_bf16(aKh, qh_v, a, 0,0,0);
      St[kt] = a;
    }

    // fixed-shift softmax in log2 space: p = exp2(mv_l2e * S - 50*l2e)
    float lsum = 0.f;
    #pragma unroll
    for(int kt=0;kt<8;kt++){
      float4 mv = *(const float4*)&Msl[kt*16 + Q*4];
      float mvr[4] = {mv.x, mv.y, mv.z, mv.w};
      #pragma unroll
      for(int r=0;r<4;r++){
        float p = EXP2F(fmaf(mvr[r], St[kt][r], -SOFT_SHIFT_L2E));
        St[kt][r] = p;
        lsum += p;
      }
    }
    lacc += lsum;

    // pack P -> bf16 pairs
    int pk[8][2];
    #pragma unroll
    for(int kt=0;kt<8;kt++){
      pk[kt][0] = pack_bf16(St[kt][0], St[kt][1]);
      pk[kt][1] = pack_bf16(St[kt][2], St[kt][3]);
    }

    // PV: O^T += V^T · P^T (chunks 0,1 -> a; 2,3 -> b)
    #pragma unroll
    for(int c=0;c<4;c++){
      union { int i[4]; bf16x8 v; } bu;
      #pragma unroll
      for(int d=0;d<4;d++){
        int srcl = (((Q&1)*2 + (d>>1))<<4) | L15;
        int vlo = __shfl(pk[2*c  ][d&1], srcl, 64);
        int vhi = __shfl(pk[2*c+1][d&1], srcl, 64);
        bu.i[d] = (Q & 2) ? vhi : vlo;
      }
      bf16x8 aV0 = *(const bf16x8*)&Vts[(c*2+0)*512 + lane*8];
      bf16x8 aV1 = *(const bf16x8*)&Vts[(c*2+1)*512 + lane*8];
      if(c < 2){
        Oa0a = __builtin_amdgcn_mfma_f32_16x16x32_bf16(aV0, bu.v, Oa0a, 0,0,0);
        Oa1a = __builtin_amdgcn_mfma_f32_16x16x32_bf16(aV1, bu.v, Oa1a, 0,0,0);
      } else {
        Oa0b = __builtin_amdgcn_mfma_f32_16x16x32_bf16(aV0, bu.v, Oa0b, 0,0,0);
        Oa1b = __builtin_amdgcn_mfma_f32_16x16x32_bf16(aV1, bu.v, Oa1b, 0,0,0);
      }
    }
    __syncthreads();
  }

  f32x4 Oa0 = Oa0a + Oa0b;
  f32x4 Oa1 = Oa1a + Oa1b;
  lacc += __shfl_xor(lacc, 16);
  lacc += __shfl_xor(lacc, 32);

  float* opp = &Opart[((size_t)(ks*16+bh)*SS + q0 + L15)*32];
  #pragma unroll
  for(int r=0;r<4;r++){
    opp[Q*4+r]    = Oa0[r];
    opp[16+Q*4+r] = Oa1[r];
  }
  if(Q==0){
    ML[(size_t)(ks*16+bh)*SS + q0 + L15] = lacc;
  }
}

// LayerNorm: one WAVE per row (64 lanes x 4 cols), pure-shfl reduction,
// no LDS, no barriers. 4 rows per block, grid = MROWS/4.
// Emits xf, pre-split xhl, and (optionally) final output.
__launch_bounds__(256)
__global__ void ln_kernel(float* __restrict__ xf, const float* __restrict__ gamma,
                          const float* __restrict__ beta, int gi,
                          us* __restrict__ xh, us* __restrict__ xl,
                          void* __restrict__ out, int write_out,
                          const int* __restrict__ flagp)
{
  const int wv = threadIdx.x >> 6;
  const int lane = threadIdx.x & 63;
  const int r = blockIdx.x*4 + wv;
  const int c0 = lane*4;
  float4 v = *(const float4*)&xf[(size_t)r*DD + c0];
  float sum = v.x+v.y+v.z+v.w;
  float sumsq = v.x*v.x + v.y*v.y + v.z*v.z + v.w*v.w;
  #pragma unroll
  for(int off=1; off<64; off<<=1){
    sum   += __shfl_xor(sum, off);
    sumsq += __shfl_xor(sumsq, off);
  }
  float mean = sum*(1.f/DD);
  float var  = sumsq*(1.f/DD) - mean*mean;
  float g = gamma[gi], bb = beta[gi];
  float sc = rsqrtf(var+LN_EPS)*g;
  float o4[4] = {(v.x-mean)*sc+bb, (v.y-mean)*sc+bb, (v.z-mean)*sc+bb, (v.w-mean)*sc+bb};
  *(float4*)&xf[(size_t)r*DD + c0] = *(float4*)o4;
  us4 h4, l4;
  #pragma unroll
  for(int j=0;j<4;j++){
    us hb = f2bf_rne(o4[j]);
    h4[j] = hb; l4[j] = f2bf_rne(o4[j] - us2f(hb));
  }
  size_t xi = xhl_idx(r, c0);   // cols c0..c0+3 are contiguous in frag-major
  *(us4*)&xh[xi] = h4;
  *(us4*)&xl[xi] = l4;
  if(write_out){
    if(*flagp){
      *(float4*)&((float*)out)[(size_t)r*DD + c0] = *(float4*)o4;
    } else {
      bf16* op = (bf16*)out + (size_t)r*DD + c0;
      #pragma unroll
      for(int j=0;j<4;j++) op[j] = __float2bfloat16(o4[j]);
    }
  }
}

extern "C" void kernel_launch(void* const* d_in, const int* in_sizes, int n_in,
                              void* d_out, int out_size, void* d_ws, size_t ws_size,
                              hipStream_t stream)
{
  float* ws = (float*)d_ws;
  int* flagp = (int*)d_ws;

  float* xf  = ws + O_XF;
  us* QHb = (us*)(ws + O_QB);
  us* QLb = QHb + 1048576;
  us* KH = (us*)(ws + O_KH);
  us* KL = (us*)(ws + O_KL);
  us* VT = (us*)(ws + O_VT);
  us* XH = (us*)(ws + O_XH);
  us* XL = (us*)(ws + O_XL);
  float* Opart = ws + O_OP;
  float* ML  = ws + O_ML;
  float* fh  = Opart;                   // FFN hidden aliases Opart (dead after Wo-GEMM)
  float* b1f = ws + O_B1;
  float* b2f_ = ws + O_B2;
  float* gmf = ws + O_GM;
  float* btf = ws + O_BT;
  us* prep = (us*)(ws + O_PREP);

  detect_kernel<<<1,256,0,stream>>>((const us*)d_in[0], in_sizes[0], flagp);
  conv_prep<<<PREP_BLOCKS+CONV_BLOCKS,256,0,stream>>>(
      d_in[0], d_in[1], d_in[2], d_in[3], d_in[4], d_in[5],
      d_in[6], d_in[7], d_in[8], d_in[9], d_in[10], d_in[11],
      ws, flagp);

  for(int i=0;i<NL;i++){
    const float* b1i = b1f + (size_t)i*DFF;
    const float* b2i = b2f_ + (size_t)i*DD;

    dim3 g0(64, 12);
    gemm_mfma<0,1><<<g0,256,0,stream>>>(nullptr, XH, XL, nullptr, nullptr,
                                        prep+PQH+(size_t)i*196608, prep+PQL+(size_t)i*196608,
                                        nullptr, nullptr, nullptr,
                                        QHb, QLb, KH, KL, VT, 768, 256);
    attn_kernel<<<1024,256,0,stream>>>(QHb, QLb, KH, KL, VT, ws + O_MASK, Opart, ML);
    dim3 g1(64, 4);
    gemm_mfma<1,2><<<g1,256,0,stream>>>(nullptr, nullptr, nullptr, Opart, ML,
                                        prep+POH+(size_t)i*65536, prep+POL+(size_t)i*65536,
                                        nullptr, xf, xf,
                                        nullptr, nullptr, nullptr, nullptr, nullptr, 256, 256);
    ln_kernel<<<MROWS/4,256,0,stream>>>(xf, gmf, btf, 2*i, XH, XL, d_out, 0, flagp);
    dim3 g2(64, 8);
    gemm_mfma<2,1><<<g2,256,0,stream>>>(nullptr, XH, XL, nullptr, nullptr,
                                        prep+P1H+(size_t)i*131072, prep+P1L+(size_t)i*131072,
                                        b1i, nullptr, fh,
                                        nullptr, nullptr, nullptr, nullptr, nullptr, 512, 256);
    dim3 g3(64, 4);
    gemm_mfma<3,0><<<g3,256,0,stream>>>(fh, nullptr, nullptr, nullptr, nullptr,
                                        prep+P2H+(size_t)i*131072, prep+P2L+(size_t)i*131072,
                                        b2i, xf, xf,
                                        nullptr, nullptr, nullptr, nullptr, nullptr, 256, 512);
    ln_kernel<<<MROWS/4,256,0,stream>>>(xf, gmf, btf, 2*i+1, XH, XL, d_out, (i==NL-1)?1:0, flagp);
  }
}

// Round 15
// 274.914 us; speedup vs baseline: 1.0470x; 1.0161x over previous
//
#include <hip/hip_runtime.h>
#include <hip/hip_bf16.h>

#define NL 2
#define NH 8
#define DKk 32
#define DVv 32
#define DFF 512
#define DD 256
#define BB 2
#define SS 2048
#define MROWS (BB*SS)            // 4096
#define LN_EPS 1e-14f
#define L2E 1.4426950408889634f
#define SOFT_SHIFT_L2E (50.0f*L2E)   // fixed softmax shift, in log2 units

typedef __hip_bfloat16 bf16;
typedef unsigned short us;
typedef short bf16x8 __attribute__((ext_vector_type(8)));   // 8 bf16 = 4 VGPRs
typedef float f32x4  __attribute__((ext_vector_type(4)));
typedef unsigned short us4 __attribute__((ext_vector_type(4)));

// ---- workspace layout (floats) ----
#define O_XF   256
#define O_QB   (O_XF+1048576)      // QH (1048576 us) + QL (1048576 us) frag-major
#define O_KH   (O_QB+1048576)
#define O_KL   (O_KH+524288)
#define O_VT   (O_KL+524288)
#define O_XH   (O_VT+524288)       // x pre-split hi (1048576 us)
#define O_XL   (O_XH+524288)       // x pre-split lo
#define O_OP   (O_XL+524288)       // 2097152: key-split x2 partial O (fh aliases)
#define O_ML   (O_OP+2097152)      // 65536: key-split l (m is constant)
#define O_MASK (O_ML+65536)
#define O_B1   (O_MASK+4096)
#define O_B2   (O_B1+1024)
#define O_GM   (O_B2+512)
#define O_BT   (O_GM+4)
#define O_PREP (O_BT+4)
// conv segments: x | mask | b1 | b2 | gamma | beta (weights prep'd from raw inputs)
#define CONV_TOTAL (1048576+4096+1024+512+4+4)
#define CONV_BLOCKS ((CONV_TOTAL+255)/256)
#define PREP_BLOCKS 512
// prep region offsets in ushorts (relative to (us*)(ws+O_PREP))
#define PQH 0u
#define PQL 393216u
#define POH 786432u
#define POL 917504u
#define P1H 1048576u
#define P1L 1310720u
#define P2H 1572864u
#define P2L 1835008u

__device__ __forceinline__ float us2f(us u){
  unsigned int v = ((unsigned int)u) << 16; float f;
  __builtin_memcpy(&f, &v, 4); return f;
}
__device__ __forceinline__ us f2bf_rne(float f){
  unsigned int b = __float_as_uint(f);
  b += 0x7FFFu + ((b>>16)&1u);
  return (us)(b>>16);
}

#if __has_builtin(__builtin_amdgcn_exp2f)
#define EXP2F(x) __builtin_amdgcn_exp2f(x)
#else
#define EXP2F(x) exp2f(x)
#endif

#if __has_builtin(__builtin_amdgcn_cvt_pk_bf16_f32)
typedef __bf16 bf16x2_t __attribute__((ext_vector_type(2)));
__device__ __forceinline__ int pack_bf16(float a, float b){
  bf16x2_t r = __builtin_amdgcn_cvt_pk_bf16_f32(a, b);
  int i; __builtin_memcpy(&i, &r, 4); return i;
}
#else
__device__ __forceinline__ int pack_bf16(float a, float b){
  int b0 = __float_as_int(a) + 0x8000;
  int b1 = __float_as_int(b) + 0x8000;
  return (b1 & 0xFFFF0000) | ((int)((unsigned)b0 >> 16));
}
#endif

// Async global->LDS 16B copy (lane-linear layouts only).
__device__ __forceinline__ void gl_lds16(const us* g, us* l){
  __builtin_amdgcn_global_load_lds(
    (const __attribute__((address_space(1))) unsigned int*)g,
    (__attribute__((address_space(3))) unsigned int*)l, 16, 0, 0);
}

// x pre-split frag-major index for element (row, col), K=256 tiling.
__device__ __forceinline__ size_t xhl_idx(int row, int col){
  int rt = row>>6, rg = (row>>4)&3, L15 = row&15;
  int kc = col>>5, Q = (col>>3)&3, j = col&7;
  return ((size_t)(rt*8+kc))*2048 + rg*512 + Q*128 + L15*8 + j;
}

// Detect whether inputs are bf16 (flag=0) or fp32 (flag=1).
__global__ void detect_kernel(const us* __restrict__ x, int n, int* __restrict__ flagp){
  __shared__ int bad;
  if(threadIdx.x==0) bad = 0;
  __syncthreads();
  int lim = n < 4096 ? n : 4096;
  int mybad = 0;
  for(int i=threadIdx.x; i<lim; i+=256){
    float f = us2f(x[i]);
    if(!(fabsf(f) < 1e3f)) mybad = 1;
  }
  if(mybad) atomicOr(&bad, 1);
  __syncthreads();
  if(threadIdx.x==0) *flagp = bad ? 1 : 0;
}

__device__ __forceinline__ float conv1(const void* src, size_t i, int flag){
  if(flag) return ((const float*)src)[i];
  return us2f(((const us*)src)[i]);
}

// Build fragment-major hi/lo bf16 B-operands reading RAW (flag-dtype) weights.
__device__ __forceinline__ void prep_b_raw(const void* W0, const void* W1v, const void* W2v,
                                           int baseoff, us* __restrict__ Bh, us* __restrict__ Bl,
                                           int Kd, int Nd, int qkv, int g, int flag)
{
  int total = (Kd/32)*(Nd/16)*64;
  if(g >= total) return;
  int lane = g & 63, fi = g >> 6;
  int ncN = Nd/16;
  int nc = fi % ncN, kc = fi / ncN;
  int Q = lane>>4, L15 = lane&15;
  int n = nc*16 + L15;
  const void* src;
  int off0, stride;
  if(qkv){
    int sec = n>>8, h = (n>>5)&7, kq = n&31;
    src = (sec==0)?W0:((sec==1)?W1v:W2v);
    off0 = baseoff + h*8192 + kq;
    stride = 32;
  } else {
    src = W0;
    off0 = baseoff + n;
    stride = Nd;
  }
  #pragma unroll
  for(int j=0;j<8;j++){
    int k = kc*32 + Q*8 + j;
    float v = conv1(src, (size_t)off0 + (size_t)k*stride, flag);
    us hb = f2bf_rne(v);
    Bh[(size_t)g*8 + j] = hb;
    Bl[(size_t)g*8 + j] = f2bf_rne(v - us2f(hb));
  }
}

// Fused: weight prep (blocks 0..511) + input conversion (remaining blocks).
__global__ void conv_prep(const void* s0, const void* s1, const void* sWq, const void* sWk,
                          const void* sWv, const void* sWo, const void* sW1, const void* sb1,
                          const void* sW2, const void* sb2, const void* sgm, const void* sbt,
                          float* __restrict__ ws, const int* __restrict__ flagp)
{
  int flag = *flagp;
  int b = blockIdx.x;
  if(b < PREP_BLOCKS){
    int layer = b >> 8, lb = b & 255;
    us* prep = (us*)(ws + O_PREP);
    if(lb < 96){
      int g = lb*256 + threadIdx.x;
      prep_b_raw(sWq, sWk, sWv, layer*65536, prep+PQH+(size_t)layer*196608,
                 prep+PQL+(size_t)layer*196608, 256, 768, 1, g, flag);
    } else if(lb < 128){
      int g = (lb-96)*256 + threadIdx.x;
      prep_b_raw(sWo, nullptr, nullptr, layer*65536, prep+POH+(size_t)layer*65536,
                 prep+POL+(size_t)layer*65536, 256, 256, 0, g, flag);
    } else if(lb < 192){
      int g = (lb-128)*256 + threadIdx.x;
      prep_b_raw(sW1, nullptr, nullptr, layer*131072, prep+P1H+(size_t)layer*131072,
                 prep+P1L+(size_t)layer*131072, 256, 512, 0, g, flag);
    } else {
      int g = (lb-192)*256 + threadIdx.x;
      prep_b_raw(sW2, nullptr, nullptr, layer*131072, prep+P2H+(size_t)layer*131072,
                 prep+P2L+(size_t)layer*131072, 512, 256, 0, g, flag);
    }
    return;
  }
  int g = (b - PREP_BLOCKS)*256 + threadIdx.x;
  if(g < 1048576){
    float v = conv1(s0, g, flag);
    ws[O_XF+g] = v;
    us hb = f2bf_rne(v);
    us lb = f2bf_rne(v - us2f(hb));
    size_t xi = xhl_idx(g>>8, g&255);
    ((us*)(ws+O_XH))[xi] = hb;
    ((us*)(ws+O_XL))[xi] = lb;
    return;
  }
  g -= 1048576;
  if(g < 4096){ ws[O_MASK+g] = conv1(s1, g, flag)*L2E; return; }
  g -= 4096;
  if(g < 1024){ ws[O_B1+g] = conv1(sb1, g, flag); return; }
  g -= 1024;
  if(g < 512){ ws[O_B2+g] = conv1(sb2, g, flag); return; }
  g -= 512;
  if(g < 4){ ws[O_GM+g] = conv1(sgm, g, flag); return; }
  g -= 4;
  if(g < 4){ ws[O_BT+g] = conv1(sbt, g, flag); return; }
}

// Split-bf16 MFMA GEMM (64x64 tile, 4 waves, 3 MFMAs/frag/K32).
// ASRC 1: A pre-split (global_load_lds).
// MODE 0: QKV -> QH/QL, KH/KL, VT frag-major bf16. MODE 2: relu(acc+bias).
template<int MODE, int ASRC>
__launch_bounds__(256)
__global__ void gemm_mfma(const float* __restrict__ A,
                          const us* __restrict__ Axh, const us* __restrict__ Axl,
                          const us* __restrict__ Bh, const us* __restrict__ Bl,
                          const float* __restrict__ bias,
                          float* __restrict__ O,
                          us* __restrict__ QH, us* __restrict__ QL,
                          us* __restrict__ KH, us* __restrict__ KL, us* __restrict__ VT,
                          int Ncols, int Kdim)
{
  __shared__ __align__(16) us Ah[2048], Al[2048];
  __shared__ __align__(16) us Bhs[2048], Bls[2048];
  const int t = threadIdx.x;
  const int w = t>>6, lane = t&63;
  const int Q = lane>>4, L15 = lane&15;
  const int row0 = blockIdx.x*64;
  const int nc0 = blockIdx.y*4;
  const int col0 = blockIdx.y*64;

  f32x4 acc[2][2];
  #pragma unroll
  for(int i=0;i<2;i++)
    #pragma unroll
    for(int j=0;j<2;j++) acc[i][j] = (f32x4){0.f,0.f,0.f,0.f};

  const int nKc = Kdim>>5;
  const int ncW = Ncols>>4;

  for(int kc=0; kc<nKc; kc++){
    {
      size_t abase = ((size_t)(blockIdx.x*nKc + kc))*2048;
      gl_lds16(&Axh[abase + (size_t)t*8], &Ah[t*8]);
      gl_lds16(&Axl[abase + (size_t)t*8], &Al[t*8]);
      size_t gidx = ((size_t)(kc*ncW + nc0 + w)*64 + lane)*8;
      gl_lds16(&Bh[gidx], &Bhs[t*8]);
      gl_lds16(&Bl[gidx], &Bls[t*8]);
    }
    __syncthreads();

    bf16x8 aAh[2], aAl[2], bBh[2], bBl[2];
    #pragma unroll
    for(int rg2=0;rg2<2;rg2++){
      int rg = (w&1)*2 + rg2;
      aAh[rg2] = *(const bf16x8*)&Ah[rg*512 + lane*8];
      aAl[rg2] = *(const bf16x8*)&Al[rg*512 + lane*8];
    }
    #pragma unroll
    for(int cg2=0;cg2<2;cg2++){
      int nc = (w>>1)*2 + cg2;
      bBh[cg2] = *(const bf16x8*)&Bhs[nc*512 + lane*8];
      bBl[cg2] = *(const bf16x8*)&Bls[nc*512 + lane*8];
    }
    #pragma unroll
    for(int rg2=0;rg2<2;rg2++)
      #pragma unroll
      for(int cg2=0;cg2<2;cg2++){
        acc[rg2][cg2] = __builtin_amdgcn_mfma_f32_16x16x32_bf16(aAl[rg2], bBh[cg2], acc[rg2][cg2], 0,0,0);
        acc[rg2][cg2] = __builtin_amdgcn_mfma_f32_16x16x32_bf16(aAh[rg2], bBl[cg2], acc[rg2][cg2], 0,0,0);
        acc[rg2][cg2] = __builtin_amdgcn_mfma_f32_16x16x32_bf16(aAh[rg2], bBh[cg2], acc[rg2][cg2], 0,0,0);
      }
    __syncthreads();
  }

  #pragma unroll
  for(int rg2=0;rg2<2;rg2++)
    #pragma unroll
    for(int cg2=0;cg2<2;cg2++)
      #pragma unroll
      for(int r=0;r<4;r++){
        int row = row0 + (w&1)*32 + rg2*16 + Q*4 + r;
        int c   = col0 + (w>>1)*32 + cg2*16 + L15;
        float va = acc[rg2][cg2][r];
        if(MODE==0){
          int b_ = row>>11, s_ = row&2047;
          int sec = c>>8, h = (c>>5)&7, kq = c&31;
          int bh = b_*NH + h;
          size_t idx = ((size_t)(bh*128 + (s_>>4))*64 + (kq>>3)*16 + (s_&15))*8 + (kq&7);
          if(sec==0){
            us hb = f2bf_rne(va);
            QH[idx] = hb; QL[idx] = f2bf_rne(va - us2f(hb));
          } else if(sec==1){
            us hb = f2bf_rne(va);
            KH[idx] = hb; KL[idx] = f2bf_rne(va - us2f(hb));
          } else {
            size_t vidx = ((size_t)((bh*64 + (s_>>5))*2 + (kq>>4))*64 + ((s_&31)>>3)*16 + (kq&15))*8 + (s_&7);
            VT[vidx] = f2bf_rne(va);
          }
        } else {
          float v = va + bias[c];
          O[(size_t)row*Ncols + c] = v>0.f ? v : 0.f;
        }
      }
}

// Fused narrow-N GEMM + residual (+bias) + LayerNorm, N=256.
// Tile 16 rows x 256 cols; grid 256 blocks; wave w = cols [w*64,+64), 4 frags.
// SRC 0: Wo — A = merged attn partials (h == kc). SRC 1: FFN2 — A = fh fp32 + bias.
// Emits xf (ln output), frag-major xhl, optionally final d_out.
template<int SRC>
__launch_bounds__(256)
__global__ void gemm_ln(const float* __restrict__ A,
                        const float* __restrict__ OpartA, const float* __restrict__ MLA,
                        const us* __restrict__ Bh, const us* __restrict__ Bl,
                        const float* __restrict__ bias, const float* __restrict__ res,
                        float* __restrict__ xf,
                        us* __restrict__ xh, us* __restrict__ xl,
                        const float* __restrict__ gamma, const float* __restrict__ beta, int gi,
                        void* __restrict__ out, int write_out,
                        const int* __restrict__ flagp, int Kdim)
{
  __shared__ __align__(16) us Ah[512], Al[512];       // 16r x 32k frag-major
  __shared__ __align__(16) us Bhs[8192], Bls[8192];   // 32k x 256n frag-major
  __shared__ float lred[128];                          // [wave][row][s,sq]
  const int t = threadIdx.x;
  const int w = t>>6, lane = t&63;
  const int Q = lane>>4, L15 = lane&15;
  const int row0 = blockIdx.x*16;
  const int nKc = Kdim>>5;

  f32x4 acc[4];
  #pragma unroll
  for(int cg=0;cg<4;cg++) acc[cg] = (f32x4){0.f,0.f,0.f,0.f};

  for(int kc=0; kc<nKc; kc++){
    if(t < 128){
      int r = t>>3;            // 0..15
      int kl = (t&7)*4;        // 0..28
      float4 v;
      if(SRC==0){
        int row = row0 + r;
        int b_ = row>>11, s_ = row&2047;
        size_t i0 = (size_t)(b_*8 + kc)*2048 + s_;    // h == kc (Kdim=256)
        float l = MLA[i0] + MLA[i0+32768];
        float inv = 1.f/l;
        float4 o0 = *(const float4*)&OpartA[i0*32 + kl];
        float4 o1 = *(const float4*)&OpartA[(i0+32768)*32 + kl];
        v.x=(o0.x+o1.x)*inv; v.y=(o0.y+o1.y)*inv;
        v.z=(o0.z+o1.z)*inv; v.w=(o0.w+o1.w)*inv;
      } else {
        v = *(const float4*)&A[(size_t)(row0+r)*Kdim + kc*32 + kl];
      }
      float f[4] = {v.x, v.y, v.z, v.w};
      us4 h4, l4;
      #pragma unroll
      for(int j=0;j<4;j++){
        us hb = f2bf_rne(f[j]);
        h4[j] = hb; l4[j] = f2bf_rne(f[j] - us2f(hb));
      }
      int off = (kl>>3)*128 + r*8 + (kl&7);
      *(us4*)&Ah[off] = h4;
      *(us4*)&Al[off] = l4;
    }
    #pragma unroll
    for(int ii=0; ii<4; ii++){
      int unit = w + ii*4;     // 0..15
      size_t gidx = ((size_t)(kc*16 + unit)*64 + lane)*8;
      gl_lds16(&Bh[gidx], &Bhs[unit*512 + lane*8]);
      gl_lds16(&Bl[gidx], &Bls[unit*512 + lane*8]);
    }
    __syncthreads();

    bf16x8 aAh = *(const bf16x8*)&Ah[lane*8];
    bf16x8 aAl = *(const bf16x8*)&Al[lane*8];
    #pragma unroll
    for(int cg=0;cg<4;cg++){
      int unit = w*4 + cg;
      bf16x8 bBh = *(const bf16x8*)&Bhs[unit*512 + lane*8];
      bf16x8 bBl = *(const bf16x8*)&Bls[unit*512 + lane*8];
      acc[cg] = __builtin_amdgcn_mfma_f32_16x16x32_bf16(aAl, bBh, acc[cg], 0,0,0);
      acc[cg] = __builtin_amdgcn_mfma_f32_16x16x32_bf16(aAh, bBl, acc[cg], 0,0,0);
      acc[cg] = __builtin_amdgcn_mfma_f32_16x16x32_bf16(aAh, bBh, acc[cg], 0,0,0);
    }
    __syncthreads();
  }

  // epilogue: residual (+bias), then LN over the full 256-col rows
  float tmp[4][4];             // [cg][r]
  #pragma unroll
  for(int cg=0;cg<4;cg++)
    #pragma unroll
    for(int r=0;r<4;r++){
      int row = row0 + Q*4 + r;
      int c = w*64 + cg*16 + L15;
      float v = acc[cg][r] + res[(size_t)row*DD + c];
      if(SRC==1) v += bias[c];
      tmp[cg][r] = v;
    }
  float s[4], sq[4];
  #pragma unroll
  for(int r=0;r<4;r++){
    s[r]  = tmp[0][r]+tmp[1][r]+tmp[2][r]+tmp[3][r];
    sq[r] = tmp[0][r]*tmp[0][r]+tmp[1][r]*tmp[1][r]+tmp[2][r]*tmp[2][r]+tmp[3][r]*tmp[3][r];
  }
  #pragma unroll
  for(int off=1; off<16; off<<=1)
    #pragma unroll
    for(int r=0;r<4;r++){
      s[r]  += __shfl_xor(s[r], off);
      sq[r] += __shfl_xor(sq[r], off);
    }
  if(L15==0){
    #pragma unroll
    for(int r=0;r<4;r++){
      int rl = Q*4 + r;
      lred[(w*16 + rl)*2]   = s[r];
      lred[(w*16 + rl)*2+1] = sq[r];
    }
  }
  __syncthreads();
  float g = gamma[gi], bb = beta[gi];
  float scv[4], mnv[4];
  #pragma unroll
  for(int r=0;r<4;r++){
    int rl = Q*4 + r;
    float S  = lred[rl*2]   + lred[(16+rl)*2]   + lred[(32+rl)*2]   + lred[(48+rl)*2];
    float SQ = lred[rl*2+1] + lred[(16+rl)*2+1] + lred[(32+rl)*2+1] + lred[(48+rl)*2+1];
    float mean = S*(1.f/DD);
    float var  = SQ*(1.f/DD) - mean*mean;
    scv[r] = rsqrtf(var+LN_EPS)*g;
    mnv[r] = mean;
  }
  int flag = write_out ? *flagp : 0;
  #pragma unroll
  for(int cg=0;cg<4;cg++)
    #pragma unroll
    for(int r=0;r<4;r++){
      int row = row0 + Q*4 + r;
      int c = w*64 + cg*16 + L15;
      float val = (tmp[cg][r]-mnv[r])*scv[r] + bb;
      xf[(size_t)row*DD + c] = val;
      us hb = f2bf_rne(val);
      size_t xi = xhl_idx(row, c);
      xh[xi] = hb;
      xl[xi] = f2bf_rne(val - us2f(hb));
      if(write_out){
        if(flag) ((float*)out)[(size_t)row*DD + c] = val;
        else     ((bf16*)out)[(size_t)row*DD + c] = __float2bfloat16(val);
      }
    }
}

// MFMA flash attention v7: exp2 softmax, cvt_pk pack, frag-major Q,
// key-split x2, async LDS staging.
__launch_bounds__(256)
__global__ void attn_kernel(const us* __restrict__ QH, const us* __restrict__ QL,
                            const us* __restrict__ KH, const us* __restrict__ KL,
                            const us* __restrict__ VT,
                            const float* __restrict__ mask,
                            float* __restrict__ Opart, float* __restrict__ ML)
{
  __shared__ __align__(16) us Khs[4096], Kls[4096], Vts[4096];
  __shared__ __align__(16) float Msl[128];
  const int t = threadIdx.x;
  const int bh = blockIdx.x >> 6;
  const int qt = (blockIdx.x & 63) >> 1;
  const int ks = blockIdx.x & 1;
  const int b_ = bh >> 3;
  const int wv = t >> 6;
  const int lane = t & 63;
  const int Q = lane >> 4, L15 = lane & 15;
  const int q0 = qt*64 + wv*16;

  size_t qidx = ((size_t)(bh*128 + qt*4 + wv)*64 + lane)*8;
  const bf16x8 qh_v = *(const bf16x8*)&QH[qidx];
  const bf16x8 ql_v = *(const bf16x8*)&QL[qidx];

  const us* KHbh = KH + (size_t)bh*65536;
  const us* KLbh = KL + (size_t)bh*65536;
  const us* VTbh = VT + (size_t)bh*65536;

  f32x4 Oa0a = {0.f,0.f,0.f,0.f}, Oa0b = {0.f,0.f,0.f,0.f};
  f32x4 Oa1a = {0.f,0.f,0.f,0.f}, Oa1b = {0.f,0.f,0.f,0.f};
  float lacc = 0.f;

  const int kend = ks*1024 + 1024;
  for(int t0 = ks*1024; t0 < kend; t0 += 128){
    {
      size_t kbase = (size_t)(t0>>4)*512;
      size_t vbase = (size_t)(t0>>5)*1024;
      #pragma unroll
      for(int ii=0; ii<2; ii++){
        int s = t + ii*256;
        gl_lds16(&KHbh[kbase + (size_t)s*8], &Khs[s*8]);
        gl_lds16(&KLbh[kbase + (size_t)s*8], &Kls[s*8]);
        gl_lds16(&VTbh[vbase + (size_t)s*8], &Vts[s*8]);
      }
      if(t < 128) Msl[t] = mask[b_*SS + t0 + t];   // mask pre-scaled by log2e
    }
    __syncthreads();

    // QK^T -> S^T (3 MFMAs per 16-key tile, 8 tiles)
    f32x4 St[8];
    const f32x4 zz = {0.f,0.f,0.f,0.f};
    #pragma unroll
    for(int kt=0;kt<8;kt++){
      bf16x8 aKh = *(const bf16x8*)&Khs[kt*512 + lane*8];
      bf16x8 aKl = *(const bf16x8*)&Kls[kt*512 + lane*8];
      f32x4 a = __builtin_amdgcn_mfma_f32_16x16x32_bf16(aKl, qh_v, zz, 0,0,0);
      a = __builtin_amdgcn_mfma_f32_16x16x32_bf16(aKh, ql_v, a, 0,0,0);
      a = __builtin_amdgcn_mfma_f32_16x16x32_bf16(aKh, qh_v, a, 0,0,0);
      St[kt] = a;
    }

    // fixed-shift softmax in log2 space: p = exp2(mv_l2e * S - 50*l2e)
    float lsum = 0.f;
    #pragma unroll
    for(int kt=0;kt<8;kt++){
      float4 mv = *(const float4*)&Msl[kt*16 + Q*4];
      float mvr[4] = {mv.x, mv.y, mv.z, mv.w};
      #pragma unroll
      for(int r=0;r<4;r++){
        float p = EXP2F(fmaf(mvr[r], St[kt][r], -SOFT_SHIFT_L2E));
        St[kt][r] = p;
        lsum += p;
      }
    }
    lacc += lsum;

    // pack P -> bf16 pairs
    int pk[8][2];
    #pragma unroll
    for(int kt=0;kt<8;kt++){
      pk[kt][0] = pack_bf16(St[kt][0], St[kt][1]);
      pk[kt][1] = pack_bf16(St[kt][2], St[kt][3]);
    }

    // PV: O^T += V^T · P^T (chunks 0,1 -> a; 2,3 -> b)
    #pragma unroll
    for(int c=0;c<4;c++){
      union { int i[4]; bf16x8 v; } bu;
      #pragma unroll
      for(int d=0;d<4;d++){
        int srcl = (((Q&1)*2 + (d>>1))<<4) | L15;
        int vlo = __shfl(pk[2*c  ][d&1], srcl, 64);
        int vhi = __shfl(pk[2*c+1][d&1], srcl, 64);
        bu.i[d] = (Q & 2) ? vhi : vlo;
      }
      bf16x8 aV0 = *(const bf16x8*)&Vts[(c*2+0)*512 + lane*8];
      bf16x8 aV1 = *(const bf16x8*)&Vts[(c*2+1)*512 + lane*8];
      if(c < 2){
        Oa0a = __builtin_amdgcn_mfma_f32_16x16x32_bf16(aV0, bu.v, Oa0a, 0,0,0);
        Oa1a = __builtin_amdgcn_mfma_f32_16x16x32_bf16(aV1, bu.v, Oa1a, 0,0,0);
      } else {
        Oa0b = __builtin_amdgcn_mfma_f32_16x16x32_bf16(aV0, bu.v, Oa0b, 0,0,0);
        Oa1b = __builtin_amdgcn_mfma_f32_16x16x32_bf16(aV1, bu.v, Oa1b, 0,0,0);
      }
    }
    __syncthreads();
  }

  f32x4 Oa0 = Oa0a + Oa0b;
  f32x4 Oa1 = Oa1a + Oa1b;
  lacc += __shfl_xor(lacc, 16);
  lacc += __shfl_xor(lacc, 32);

  float* opp = &Opart[((size_t)(ks*16+bh)*SS + q0 + L15)*32];
  #pragma unroll
  for(int r=0;r<4;r++){
    opp[Q*4+r]    = Oa0[r];
    opp[16+Q*4+r] = Oa1[r];
  }
  if(Q==0){
    ML[(size_t)(ks*16+bh)*SS + q0 + L15] = lacc;
  }
}

extern "C" void kernel_launch(void* const* d_in, const int* in_sizes, int n_in,
                              void* d_out, int out_size, void* d_ws, size_t ws_size,
                              hipStream_t stream)
{
  float* ws = (float*)d_ws;
  int* flagp = (int*)d_ws;

  float* xf  = ws + O_XF;
  us* QHb = (us*)(ws + O_QB);
  us* QLb = QHb + 1048576;
  us* KH = (us*)(ws + O_KH);
  us* KL = (us*)(ws + O_KL);
  us* VT = (us*)(ws + O_VT);
  us* XH = (us*)(ws + O_XH);
  us* XL = (us*)(ws + O_XL);
  float* Opart = ws + O_OP;
  float* ML  = ws + O_ML;
  float* fh  = Opart;                   // FFN hidden aliases Opart (dead after Wo-fused)
  float* b1f = ws + O_B1;
  float* b2f_ = ws + O_B2;
  float* gmf = ws + O_GM;
  float* btf = ws + O_BT;
  us* prep = (us*)(ws + O_PREP);

  detect_kernel<<<1,256,0,stream>>>((const us*)d_in[0], in_sizes[0], flagp);
  conv_prep<<<PREP_BLOCKS+CONV_BLOCKS,256,0,stream>>>(
      d_in[0], d_in[1], d_in[2], d_in[3], d_in[4], d_in[5],
      d_in[6], d_in[7], d_in[8], d_in[9], d_in[10], d_in[11],
      ws, flagp);

  for(int i=0;i<NL;i++){
    const float* b1i = b1f + (size_t)i*DFF;
    const float* b2i = b2f_ + (size_t)i*DD;

    dim3 g0(64, 12);
    gemm_mfma<0,1><<<g0,256,0,stream>>>(nullptr, XH, XL,
                                        prep+PQH+(size_t)i*196608, prep+PQL+(size_t)i*196608,
                                        nullptr, nullptr,
                                        QHb, QLb, KH, KL, VT, 768, 256);
    attn_kernel<<<1024,256,0,stream>>>(QHb, QLb, KH, KL, VT, ws + O_MASK, Opart, ML);
    gemm_ln<0><<<256,256,0,stream>>>(nullptr, Opart, ML,
                                     prep+POH+(size_t)i*65536, prep+POL+(size_t)i*65536,
                                     nullptr, xf, xf, XH, XL,
                                     gmf, btf, 2*i, d_out, 0, flagp, 256);
    dim3 g2(64, 8);
    gemm_mfma<2,1><<<g2,256,0,stream>>>(nullptr, XH, XL,
                                        prep+P1H+(size_t)i*131072, prep+P1L+(size_t)i*131072,
                                        b1i, fh,
                                        nullptr, nullptr, nullptr, nullptr, nullptr, 512, 256);
    gemm_ln<1><<<256,256,0,stream>>>(fh, nullptr, nullptr,
                                     prep+P2H+(size_t)i*131072, prep+P2L+(size_t)i*131072,
                                     b2i, xf, xf, XH, XL,
                                     gmf, btf, 2*i+1, d_out, (i==NL-1)?1:0, flagp, 512);
  }
}

// Round 16
// 270.657 us; speedup vs baseline: 1.0635x; 1.0157x over previous
//
#include <hip/hip_runtime.h>
#include <hip/hip_bf16.h>

#define NL 2
#define NH 8
#define DKk 32
#define DVv 32
#define DFF 512
#define DD 256
#define BB 2
#define SS 2048
#define MROWS (BB*SS)            // 4096
#define LN_EPS 1e-14f
#define L2E 1.4426950408889634f
#define SOFT_SHIFT_L2E (50.0f*L2E)   // fixed softmax shift, in log2 units

typedef __hip_bfloat16 bf16;
typedef unsigned short us;
typedef short bf16x8 __attribute__((ext_vector_type(8)));   // 8 bf16 = 4 VGPRs
typedef float f32x4  __attribute__((ext_vector_type(4)));
typedef unsigned short us4 __attribute__((ext_vector_type(4)));

// ---- workspace layout (floats) ----
#define O_XF   256
#define O_QB   (O_XF+1048576)      // QH (1048576 us) + QL (1048576 us) frag-major
#define O_KH   (O_QB+1048576)
#define O_KL   (O_KH+524288)
#define O_VT   (O_KL+524288)
#define O_XH   (O_VT+524288)       // x pre-split hi (1048576 us)
#define O_XL   (O_XH+524288)       // x pre-split lo
#define O_OP   (O_XL+524288)       // 2097152: key-split x2 partial O (fh aliases)
#define O_ML   (O_OP+2097152)      // 65536: key-split l (m is constant)
#define O_MASK (O_ML+65536)
#define O_B1   (O_MASK+4096)
#define O_B2   (O_B1+1024)
#define O_GM   (O_B2+512)
#define O_BT   (O_GM+4)
#define O_PREP (O_BT+4)
// conv segments: x | mask | b1 | b2 | gamma | beta (weights prep'd from raw inputs)
#define CONV_TOTAL (1048576+4096+1024+512+4+4)
#define CONV_BLOCKS ((CONV_TOTAL+255)/256)
#define PREP_BLOCKS 512
// prep region offsets in ushorts (relative to (us*)(ws+O_PREP))
#define PQH 0u
#define PQL 393216u
#define POH 786432u
#define POL 917504u
#define P1H 1048576u
#define P1L 1310720u
#define P2H 1572864u
#define P2L 1835008u

__device__ __forceinline__ float us2f(us u){
  unsigned int v = ((unsigned int)u) << 16; float f;
  __builtin_memcpy(&f, &v, 4); return f;
}
__device__ __forceinline__ us f2bf_rne(float f){
  unsigned int b = __float_as_uint(f);
  b += 0x7FFFu + ((b>>16)&1u);
  return (us)(b>>16);
}

#if __has_builtin(__builtin_amdgcn_exp2f)
#define EXP2F(x) __builtin_amdgcn_exp2f(x)
#else
#define EXP2F(x) exp2f(x)
#endif

#if __has_builtin(__builtin_amdgcn_cvt_pk_bf16_f32)
typedef __bf16 bf16x2_t __attribute__((ext_vector_type(2)));
__device__ __forceinline__ int pack_bf16(float a, float b){
  bf16x2_t r = __builtin_amdgcn_cvt_pk_bf16_f32(a, b);
  int i; __builtin_memcpy(&i, &r, 4); return i;
}
#else
__device__ __forceinline__ int pack_bf16(float a, float b){
  int b0 = __float_as_int(a) + 0x8000;
  int b1 = __float_as_int(b) + 0x8000;
  return (b1 & 0xFFFF0000) | ((int)((unsigned)b0 >> 16));
}
#endif

// Async global->LDS 16B copy (lane-linear layouts only).
__device__ __forceinline__ void gl_lds16(const us* g, us* l){
  __builtin_amdgcn_global_load_lds(
    (const __attribute__((address_space(1))) unsigned int*)g,
    (__attribute__((address_space(3))) unsigned int*)l, 16, 0, 0);
}

// x pre-split frag-major index for element (row, col), K=256 tiling.
__device__ __forceinline__ size_t xhl_idx(int row, int col){
  int rt = row>>6, rg = (row>>4)&3, L15 = row&15;
  int kc = col>>5, Q = (col>>3)&3, j = col&7;
  return ((size_t)(rt*8+kc))*2048 + rg*512 + Q*128 + L15*8 + j;
}

__device__ __forceinline__ float conv1(const void* src, size_t i, int flag){
  if(flag) return ((const float*)src)[i];
  return us2f(((const us*)src)[i]);
}

// Build fragment-major hi/lo bf16 B-operands reading RAW (flag-dtype) weights.
__device__ __forceinline__ void prep_b_raw(const void* W0, const void* W1v, const void* W2v,
                                           int baseoff, us* __restrict__ Bh, us* __restrict__ Bl,
                                           int Kd, int Nd, int qkv, int g, int flag)
{
  int total = (Kd/32)*(Nd/16)*64;
  if(g >= total) return;
  int lane = g & 63, fi = g >> 6;
  int ncN = Nd/16;
  int nc = fi % ncN, kc = fi / ncN;
  int Q = lane>>4, L15 = lane&15;
  int n = nc*16 + L15;
  const void* src;
  int off0, stride;
  if(qkv){
    int sec = n>>8, h = (n>>5)&7, kq = n&31;
    src = (sec==0)?W0:((sec==1)?W1v:W2v);
    off0 = baseoff + h*8192 + kq;
    stride = 32;
  } else {
    src = W0;
    off0 = baseoff + n;
    stride = Nd;
  }
  #pragma unroll
  for(int j=0;j<8;j++){
    int k = kc*32 + Q*8 + j;
    float v = conv1(src, (size_t)off0 + (size_t)k*stride, flag);
    us hb = f2bf_rne(v);
    Bh[(size_t)g*8 + j] = hb;
    Bl[(size_t)g*8 + j] = f2bf_rne(v - us2f(hb));
  }
}

// Fused: dtype-detect (per-block, from x[0:4096]) + weight prep (blocks 0..511)
// + input conversion (remaining blocks). Block 0 persists the flag for gemm_ln.
__global__ void conv_prep(const void* s0, const void* s1, const void* sWq, const void* sWk,
                          const void* sWv, const void* sWo, const void* sW1, const void* sb1,
                          const void* sW2, const void* sb2, const void* sgm, const void* sbt,
                          float* __restrict__ ws, int* __restrict__ flagp)
{
  __shared__ int fsh[4];
  int bad = 0;
  const us* xr = (const us*)s0;
  for(int i=threadIdx.x; i<4096; i+=256){
    float f = us2f(xr[i]);
    if(!(fabsf(f) < 1e3f)) bad = 1;
  }
  unsigned long long m = __ballot(bad);
  if((threadIdx.x&63)==0) fsh[threadIdx.x>>6] = (m!=0ull);
  __syncthreads();
  int flag = (fsh[0]|fsh[1]|fsh[2]|fsh[3]);
  if(blockIdx.x==0 && threadIdx.x==0) *flagp = flag;

  int b = blockIdx.x;
  if(b < PREP_BLOCKS){
    int layer = b >> 8, lb = b & 255;
    us* prep = (us*)(ws + O_PREP);
    if(lb < 96){
      int g = lb*256 + threadIdx.x;
      prep_b_raw(sWq, sWk, sWv, layer*65536, prep+PQH+(size_t)layer*196608,
                 prep+PQL+(size_t)layer*196608, 256, 768, 1, g, flag);
    } else if(lb < 128){
      int g = (lb-96)*256 + threadIdx.x;
      prep_b_raw(sWo, nullptr, nullptr, layer*65536, prep+POH+(size_t)layer*65536,
                 prep+POL+(size_t)layer*65536, 256, 256, 0, g, flag);
    } else if(lb < 192){
      int g = (lb-128)*256 + threadIdx.x;
      prep_b_raw(sW1, nullptr, nullptr, layer*131072, prep+P1H+(size_t)layer*131072,
                 prep+P1L+(size_t)layer*131072, 256, 512, 0, g, flag);
    } else {
      int g = (lb-192)*256 + threadIdx.x;
      prep_b_raw(sW2, nullptr, nullptr, layer*131072, prep+P2H+(size_t)layer*131072,
                 prep+P2L+(size_t)layer*131072, 512, 256, 0, g, flag);
    }
    return;
  }
  int g = (b - PREP_BLOCKS)*256 + threadIdx.x;
  if(g < 1048576){
    float v = conv1(s0, g, flag);
    ws[O_XF+g] = v;
    us hb = f2bf_rne(v);
    us lb = f2bf_rne(v - us2f(hb));
    size_t xi = xhl_idx(g>>8, g&255);
    ((us*)(ws+O_XH))[xi] = hb;
    ((us*)(ws+O_XL))[xi] = lb;
    return;
  }
  g -= 1048576;
  if(g < 4096){ ws[O_MASK+g] = conv1(s1, g, flag)*L2E; return; }
  g -= 4096;
  if(g < 1024){ ws[O_B1+g] = conv1(sb1, g, flag); return; }
  g -= 1024;
  if(g < 512){ ws[O_B2+g] = conv1(sb2, g, flag); return; }
  g -= 512;
  if(g < 4){ ws[O_GM+g] = conv1(sgm, g, flag); return; }
  g -= 4;
  if(g < 4){ ws[O_BT+g] = conv1(sbt, g, flag); return; }
}

// Split-bf16 MFMA GEMM (64x64 tile, 4 waves, 3 MFMAs/frag/K32), A pre-split.
// MODE 0: QKV -> QH/QL, KH/KL, VT frag-major via LDS-transposed COALESCED stores.
// MODE 2: relu(acc+bias) -> O (fp32, coalesced).
template<int MODE>
__launch_bounds__(256)
__global__ void gemm_mfma(const us* __restrict__ Axh, const us* __restrict__ Axl,
                          const us* __restrict__ Bh, const us* __restrict__ Bl,
                          const float* __restrict__ bias,
                          float* __restrict__ O,
                          us* __restrict__ QH, us* __restrict__ QL,
                          us* __restrict__ KH, us* __restrict__ KL, us* __restrict__ VT,
                          int Ncols, int Kdim)
{
  __shared__ __align__(16) us SH[9216];   // K-loop: Ah|Al|Bhs|Bls (4x2048); epi: TH(4608)|TL(4608)
  us* Ah = SH; us* Al = SH+2048; us* Bhs = SH+4096; us* Bls = SH+6144;
  const int t = threadIdx.x;
  const int w = t>>6, lane = t&63;
  const int Q = lane>>4, L15 = lane&15;
  const int row0 = blockIdx.x*64;
  const int nc0 = blockIdx.y*4;
  const int col0 = blockIdx.y*64;

  f32x4 acc[2][2];
  #pragma unroll
  for(int i=0;i<2;i++)
    #pragma unroll
    for(int j=0;j<2;j++) acc[i][j] = (f32x4){0.f,0.f,0.f,0.f};

  const int nKc = Kdim>>5;
  const int ncW = Ncols>>4;

  for(int kc=0; kc<nKc; kc++){
    {
      size_t abase = ((size_t)(blockIdx.x*nKc + kc))*2048;
      gl_lds16(&Axh[abase + (size_t)t*8], &Ah[t*8]);
      gl_lds16(&Axl[abase + (size_t)t*8], &Al[t*8]);
      size_t gidx = ((size_t)(kc*ncW + nc0 + w)*64 + lane)*8;
      gl_lds16(&Bh[gidx], &Bhs[t*8]);
      gl_lds16(&Bl[gidx], &Bls[t*8]);
    }
    __syncthreads();

    bf16x8 aAh[2], aAl[2], bBh[2], bBl[2];
    #pragma unroll
    for(int rg2=0;rg2<2;rg2++){
      int rg = (w&1)*2 + rg2;
      aAh[rg2] = *(const bf16x8*)&Ah[rg*512 + lane*8];
      aAl[rg2] = *(const bf16x8*)&Al[rg*512 + lane*8];
    }
    #pragma unroll
    for(int cg2=0;cg2<2;cg2++){
      int nc = (w>>1)*2 + cg2;
      bBh[cg2] = *(const bf16x8*)&Bhs[nc*512 + lane*8];
      bBl[cg2] = *(const bf16x8*)&Bls[nc*512 + lane*8];
    }
    #pragma unroll
    for(int rg2=0;rg2<2;rg2++)
      #pragma unroll
      for(int cg2=0;cg2<2;cg2++){
        acc[rg2][cg2] = __builtin_amdgcn_mfma_f32_16x16x32_bf16(aAl[rg2], bBh[cg2], acc[rg2][cg2], 0,0,0);
        acc[rg2][cg2] = __builtin_amdgcn_mfma_f32_16x16x32_bf16(aAh[rg2], bBl[cg2], acc[rg2][cg2], 0,0,0);
        acc[rg2][cg2] = __builtin_amdgcn_mfma_f32_16x16x32_bf16(aAh[rg2], bBh[cg2], acc[rg2][cg2], 0,0,0);
      }
    __syncthreads();
  }

  if(MODE==0){
    // phase A: hi/lo tile into LDS, row stride 72 us (16B-aligned rows)
    us* TH = SH;          // 64*72 = 4608 us
    us* TL = SH + 4608;
    #pragma unroll
    for(int rg2=0;rg2<2;rg2++)
      #pragma unroll
      for(int cg2=0;cg2<2;cg2++)
        #pragma unroll
        for(int r=0;r<4;r++){
          int rl = (w&1)*32 + rg2*16 + Q*4 + r;
          int cl = (w>>1)*32 + cg2*16 + L15;
          float va = acc[rg2][cg2][r];
          us hb = f2bf_rne(va);
          TH[rl*72+cl] = hb;
          TL[rl*72+cl] = f2bf_rne(va - us2f(hb));
        }
    __syncthreads();
    const int sec = col0>>8;                 // uniform per block
    const int h0  = (col0&255)>>5;           // uniform per block
    const int b_  = row0>>11;
    const int srow0 = row0 & 2047;
    if(sec < 2){
      us* DH = (sec==0) ? QH : KH;
      us* DL = (sec==0) ? QL : KL;
      #pragma unroll
      for(int u2=0; u2<2; u2++){
        int u = w + u2*4;                    // 0..7
        int rg = u&3, half = u>>2;
        int lbase = (rg*16 + L15)*72 + half*32 + Q*8;
        bf16x8 hv = *(const bf16x8*)&TH[lbase];
        bf16x8 lv = *(const bf16x8*)&TL[lbase];
        int bh = b_*NH + h0 + half;
        size_t dbase = ((size_t)(bh*128 + (srow0>>4) + rg)*64 + lane)*8;
        *(bf16x8*)&DH[dbase] = hv;
        *(bf16x8*)&DL[dbase] = lv;
      }
    } else {
      #pragma unroll
      for(int u2=0; u2<2; u2++){
        int u = w + u2*4;                    // 0..7
        int sgrp = u&1, kqh = (u>>1)&1, half = u>>2;
        union{ us u8[8]; bf16x8 v; } vv;
        #pragma unroll
        for(int j=0;j<8;j++){
          int rl = sgrp*32 + Q*8 + j;        // s within tile
          int cl = half*32 + kqh*16 + L15;   // dv col
          vv.u8[j] = TH[rl*72+cl];
        }
        int bh = b_*NH + h0 + half;
        size_t dbase = ((size_t)((bh*64 + (srow0>>5) + sgrp)*2 + kqh)*64 + lane)*8;
        *(bf16x8*)&VT[dbase] = vv.v;
      }
    }
  } else {
    #pragma unroll
    for(int rg2=0;rg2<2;rg2++)
      #pragma unroll
      for(int cg2=0;cg2<2;cg2++)
        #pragma unroll
        for(int r=0;r<4;r++){
          int row = row0 + (w&1)*32 + rg2*16 + Q*4 + r;
          int c   = col0 + (w>>1)*32 + cg2*16 + L15;
          float v = acc[rg2][cg2][r] + bias[c];
          O[(size_t)row*Ncols + c] = v>0.f ? v : 0.f;
        }
  }
}

// Fused narrow-N GEMM + residual (+bias) + LayerNorm, N=256 (unchanged from R15).
template<int SRC>
__launch_bounds__(256)
__global__ void gemm_ln(const float* __restrict__ A,
                        const float* __restrict__ OpartA, const float* __restrict__ MLA,
                        const us* __restrict__ Bh, const us* __restrict__ Bl,
                        const float* __restrict__ bias, const float* __restrict__ res,
                        float* __restrict__ xf,
                        us* __restrict__ xh, us* __restrict__ xl,
                        const float* __restrict__ gamma, const float* __restrict__ beta, int gi,
                        void* __restrict__ out, int write_out,
                        const int* __restrict__ flagp, int Kdim)
{
  __shared__ __align__(16) us Ah[512], Al[512];       // 16r x 32k frag-major
  __shared__ __align__(16) us Bhs[8192], Bls[8192];   // 32k x 256n frag-major
  __shared__ float lred[128];
  const int t = threadIdx.x;
  const int w = t>>6, lane = t&63;
  const int Q = lane>>4, L15 = lane&15;
  const int row0 = blockIdx.x*16;
  const int nKc = Kdim>>5;

  f32x4 acc[4];
  #pragma unroll
  for(int cg=0;cg<4;cg++) acc[cg] = (f32x4){0.f,0.f,0.f,0.f};

  for(int kc=0; kc<nKc; kc++){
    if(t < 128){
      int r = t>>3;
      int kl = (t&7)*4;
      float4 v;
      if(SRC==0){
        int row = row0 + r;
        int b_ = row>>11, s_ = row&2047;
        size_t i0 = (size_t)(b_*8 + kc)*2048 + s_;    // h == kc (Kdim=256)
        float l = MLA[i0] + MLA[i0+32768];
        float inv = 1.f/l;
        float4 o0 = *(const float4*)&OpartA[i0*32 + kl];
        float4 o1 = *(const float4*)&OpartA[(i0+32768)*32 + kl];
        v.x=(o0.x+o1.x)*inv; v.y=(o0.y+o1.y)*inv;
        v.z=(o0.z+o1.z)*inv; v.w=(o0.w+o1.w)*inv;
      } else {
        v = *(const float4*)&A[(size_t)(row0+r)*Kdim + kc*32 + kl];
      }
      float f[4] = {v.x, v.y, v.z, v.w};
      us4 h4, l4;
      #pragma unroll
      for(int j=0;j<4;j++){
        us hb = f2bf_rne(f[j]);
        h4[j] = hb; l4[j] = f2bf_rne(f[j] - us2f(hb));
      }
      int off = (kl>>3)*128 + r*8 + (kl&7);
      *(us4*)&Ah[off] = h4;
      *(us4*)&Al[off] = l4;
    }
    #pragma unroll
    for(int ii=0; ii<4; ii++){
      int unit = w + ii*4;
      size_t gidx = ((size_t)(kc*16 + unit)*64 + lane)*8;
      gl_lds16(&Bh[gidx], &Bhs[unit*512 + lane*8]);
      gl_lds16(&Bl[gidx], &Bls[unit*512 + lane*8]);
    }
    __syncthreads();

    bf16x8 aAh = *(const bf16x8*)&Ah[lane*8];
    bf16x8 aAl = *(const bf16x8*)&Al[lane*8];
    #pragma unroll
    for(int cg=0;cg<4;cg++){
      int unit = w*4 + cg;
      bf16x8 bBh = *(const bf16x8*)&Bhs[unit*512 + lane*8];
      bf16x8 bBl = *(const bf16x8*)&Bls[unit*512 + lane*8];
      acc[cg] = __builtin_amdgcn_mfma_f32_16x16x32_bf16(aAl, bBh, acc[cg], 0,0,0);
      acc[cg] = __builtin_amdgcn_mfma_f32_16x16x32_bf16(aAh, bBl, acc[cg], 0,0,0);
      acc[cg] = __builtin_amdgcn_mfma_f32_16x16x32_bf16(aAh, bBh, acc[cg], 0,0,0);
    }
    __syncthreads();
  }

  float tmp[4][4];
  #pragma unroll
  for(int cg=0;cg<4;cg++)
    #pragma unroll
    for(int r=0;r<4;r++){
      int row = row0 + Q*4 + r;
      int c = w*64 + cg*16 + L15;
      float v = acc[cg][r] + res[(size_t)row*DD + c];
      if(SRC==1) v += bias[c];
      tmp[cg][r] = v;
    }
  float s[4], sq[4];
  #pragma unroll
  for(int r=0;r<4;r++){
    s[r]  = tmp[0][r]+tmp[1][r]+tmp[2][r]+tmp[3][r];
    sq[r] = tmp[0][r]*tmp[0][r]+tmp[1][r]*tmp[1][r]+tmp[2][r]*tmp[2][r]+tmp[3][r]*tmp[3][r];
  }
  #pragma unroll
  for(int off=1; off<16; off<<=1)
    #pragma unroll
    for(int r=0;r<4;r++){
      s[r]  += __shfl_xor(s[r], off);
      sq[r] += __shfl_xor(sq[r], off);
    }
  if(L15==0){
    #pragma unroll
    for(int r=0;r<4;r++){
      int rl = Q*4 + r;
      lred[(w*16 + rl)*2]   = s[r];
      lred[(w*16 + rl)*2+1] = sq[r];
    }
  }
  __syncthreads();
  float g = gamma[gi], bb = beta[gi];
  float scv[4], mnv[4];
  #pragma unroll
  for(int r=0;r<4;r++){
    int rl = Q*4 + r;
    float S  = lred[rl*2]   + lred[(16+rl)*2]   + lred[(32+rl)*2]   + lred[(48+rl)*2];
    float SQ = lred[rl*2+1] + lred[(16+rl)*2+1] + lred[(32+rl)*2+1] + lred[(48+rl)*2+1];
    float mean = S*(1.f/DD);
    float var  = SQ*(1.f/DD) - mean*mean;
    scv[r] = rsqrtf(var+LN_EPS)*g;
    mnv[r] = mean;
  }
  int flag = write_out ? *flagp : 0;
  #pragma unroll
  for(int cg=0;cg<4;cg++)
    #pragma unroll
    for(int r=0;r<4;r++){
      int row = row0 + Q*4 + r;
      int c = w*64 + cg*16 + L15;
      float val = (tmp[cg][r]-mnv[r])*scv[r] + bb;
      xf[(size_t)row*DD + c] = val;
      us hb = f2bf_rne(val);
      size_t xi = xhl_idx(row, c);
      xh[xi] = hb;
      xl[xi] = f2bf_rne(val - us2f(hb));
      if(write_out){
        if(flag) ((float*)out)[(size_t)row*DD + c] = val;
        else     ((bf16*)out)[(size_t)row*DD + c] = __float2bfloat16(val);
      }
    }
}

// MFMA flash attention v7 (unchanged from R15).
__launch_bounds__(256)
__global__ void attn_kernel(const us* __restrict__ QH, const us* __restrict__ QL,
                            const us* __restrict__ KH, const us* __restrict__ KL,
                            const us* __restrict__ VT,
                            const float* __restrict__ mask,
                            float* __restrict__ Opart, float* __restrict__ ML)
{
  __shared__ __align__(16) us Khs[4096], Kls[4096], Vts[4096];
  __shared__ __align__(16) float Msl[128];
  const int t = threadIdx.x;
  const int bh = blockIdx.x >> 6;
  const int qt = (blockIdx.x & 63) >> 1;
  const int ks = blockIdx.x & 1;
  const int b_ = bh >> 3;
  const int wv = t >> 6;
  const int lane = t & 63;
  const int Q = lane >> 4, L15 = lane & 15;
  const int q0 = qt*64 + wv*16;

  size_t qidx = ((size_t)(bh*128 + qt*4 + wv)*64 + lane)*8;
  const bf16x8 qh_v = *(const bf16x8*)&QH[qidx];
  const bf16x8 ql_v = *(const bf16x8*)&QL[qidx];

  const us* KHbh = KH + (size_t)bh*65536;
  const us* KLbh = KL + (size_t)bh*65536;
  const us* VTbh = VT + (size_t)bh*65536;

  f32x4 Oa0a = {0.f,0.f,0.f,0.f}, Oa0b = {0.f,0.f,0.f,0.f};
  f32x4 Oa1a = {0.f,0.f,0.f,0.f}, Oa1b = {0.f,0.f,0.f,0.f};
  float lacc = 0.f;

  const int kend = ks*1024 + 1024;
  for(int t0 = ks*1024; t0 < kend; t0 += 128){
    {
      size_t kbase = (size_t)(t0>>4)*512;
      size_t vbase = (size_t)(t0>>5)*1024;
      #pragma unroll
      for(int ii=0; ii<2; ii++){
        int s = t + ii*256;
        gl_lds16(&KHbh[kbase + (size_t)s*8], &Khs[s*8]);
        gl_lds16(&KLbh[kbase + (size_t)s*8], &Kls[s*8]);
        gl_lds16(&VTbh[vbase + (size_t)s*8], &Vts[s*8]);
      }
      if(t < 128) Msl[t] = mask[b_*SS + t0 + t];   // mask pre-scaled by log2e
    }
    __syncthreads();

    f32x4 St[8];
    const f32x4 zz = {0.f,0.f,0.f,0.f};
    #pragma unroll
    for(int kt=0;kt<8;kt++){
      bf16x8 aKh = *(const bf16x8*)&Khs[kt*512 + lane*8];
      bf16x8 aKl = *(const bf16x8*)&Kls[kt*512 + lane*8];
      f32x4 a = __builtin_amdgcn_mfma_f32_16x16x32_bf16(aKl, qh_v, zz, 0,0,0);
      a = __builtin_amdgcn_mfma_f32_16x16x32_bf16(aKh, ql_v, a, 0,0,0);
      a = __builtin_amdgcn_mfma_f32_16x16x32_bf16(aKh, qh_v, a, 0,0,0);
      St[kt] = a;
    }

    float lsum = 0.f;
    #pragma unroll
    for(int kt=0;kt<8;kt++){
      float4 mv = *(const float4*)&Msl[kt*16 + Q*4];
      float mvr[4] = {mv.x, mv.y, mv.z, mv.w};
      #pragma unroll
      for(int r=0;r<4;r++){
        float p = EXP2F(fmaf(mvr[r], St[kt][r], -SOFT_SHIFT_L2E));
        St[kt][r] = p;
        lsum += p;
      }
    }
    lacc += lsum;

    int pk[8][2];
    #pragma unroll
    for(int kt=0;kt<8;kt++){
      pk[kt][0] = pack_bf16(St[kt][0], St[kt][1]);
      pk[kt][1] = pack_bf16(St[kt][2], St[kt][3]);
    }

    #pragma unroll
    for(int c=0;c<4;c++){
      union { int i[4]; bf16x8 v; } bu;
      #pragma unroll
      for(int d=0;d<4;d++){
        int srcl = (((Q&1)*2 + (d>>1))<<4) | L15;
        int vlo = __shfl(pk[2*c  ][d&1], srcl, 64);
        int vhi = __shfl(pk[2*c+1][d&1], srcl, 64);
        bu.i[d] = (Q & 2) ? vhi : vlo;
      }
      bf16x8 aV0 = *(const bf16x8*)&Vts[(c*2+0)*512 + lane*8];
      bf16x8 aV1 = *(const bf16x8*)&Vts[(c*2+1)*512 + lane*8];
      if(c < 2){
        Oa0a = __builtin_amdgcn_mfma_f32_16x16x32_bf16(aV0, bu.v, Oa0a, 0,0,0);
        Oa1a = __builtin_amdgcn_mfma_f32_16x16x32_bf16(aV1, bu.v, Oa1a, 0,0,0);
      } else {
        Oa0b = __builtin_amdgcn_mfma_f32_16x16x32_bf16(aV0, bu.v, Oa0b, 0,0,0);
        Oa1b = __builtin_amdgcn_mfma_f32_16x16x32_bf16(aV1, bu.v, Oa1b, 0,0,0);
      }
    }
    __syncthreads();
  }

  f32x4 Oa0 = Oa0a + Oa0b;
  f32x4 Oa1 = Oa1a + Oa1b;
  lacc += __shfl_xor(lacc, 16);
  lacc += __shfl_xor(lacc, 32);

  float* opp = &Opart[((size_t)(ks*16+bh)*SS + q0 + L15)*32];
  #pragma unroll
  for(int r=0;r<4;r++){
    opp[Q*4+r]    = Oa0[r];
    opp[16+Q*4+r] = Oa1[r];
  }
  if(Q==0){
    ML[(size_t)(ks*16+bh)*SS + q0 + L15] = lacc;
  }
}

extern "C" void kernel_launch(void* const* d_in, const int* in_sizes, int n_in,
                              void* d_out, int out_size, void* d_ws, size_t ws_size,
                              hipStream_t stream)
{
  float* ws = (float*)d_ws;
  int* flagp = (int*)d_ws;

  float* xf  = ws + O_XF;
  us* QHb = (us*)(ws + O_QB);
  us* QLb = QHb + 1048576;
  us* KH = (us*)(ws + O_KH);
  us* KL = (us*)(ws + O_KL);
  us* VT = (us*)(ws + O_VT);
  us* XH = (us*)(ws + O_XH);
  us* XL = (us*)(ws + O_XL);
  float* Opart = ws + O_OP;
  float* ML  = ws + O_ML;
  float* fh  = Opart;                   // FFN hidden aliases Opart (dead after Wo-fused)
  float* b1f = ws + O_B1;
  float* b2f_ = ws + O_B2;
  float* gmf = ws + O_GM;
  float* btf = ws + O_BT;
  us* prep = (us*)(ws + O_PREP);

  conv_prep<<<PREP_BLOCKS+CONV_BLOCKS,256,0,stream>>>(
      d_in[0], d_in[1], d_in[2], d_in[3], d_in[4], d_in[5],
      d_in[6], d_in[7], d_in[8], d_in[9], d_in[10], d_in[11],
      ws, flagp);

  for(int i=0;i<NL;i++){
    const float* b1i = b1f + (size_t)i*DFF;
    const float* b2i = b2f_ + (size_t)i*DD;

    dim3 g0(64, 12);
    gemm_mfma<0><<<g0,256,0,stream>>>(XH, XL,
                                      prep+PQH+(size_t)i*196608, prep+PQL+(size_t)i*196608,
                                      nullptr, nullptr,
                                      QHb, QLb, KH, KL, VT, 768, 256);
    attn_kernel<<<1024,256,0,stream>>>(QHb, QLb, KH, KL, VT, ws + O_MASK, Opart, ML);
    gemm_ln<0><<<256,256,0,stream>>>(nullptr, Opart, ML,
                                     prep+POH+(size_t)i*65536, prep+POL+(size_t)i*65536,
                                     nullptr, xf, xf, XH, XL,
                                     gmf, btf, 2*i, d_out, 0, flagp, 256);
    dim3 g2(64, 8);
    gemm_mfma<2><<<g2,256,0,stream>>>(XH, XL,
                                      prep+P1H+(size_t)i*131072, prep+P1L+(size_t)i*131072,
                                      b1i, fh,
                                      nullptr, nullptr, nullptr, nullptr, nullptr, 512, 256);
    gemm_ln<1><<<256,256,0,stream>>>(fh, nullptr, nullptr,
                                     prep+P2H+(size_t)i*131072, prep+P2L+(size_t)i*131072,
                                     b2i, xf, xf, XH, XL,
                                     gmf, btf, 2*i+1, d_out, (i==NL-1)?1:0, flagp, 512);
  }
}

// Round 17
// 269.191 us; speedup vs baseline: 1.0692x; 1.0054x over previous
//
#include <hip/hip_runtime.h>
#include <hip/hip_bf16.h>

#define NL 2
#define NH 8
#define DKk 32
#define DVv 32
#define DFF 512
#define DD 256
#define BB 2
#define SS 2048
#define MROWS (BB*SS)            // 4096
#define LN_EPS 1e-14f
#define L2E 1.4426950408889634f
#define SOFT_SHIFT_L2E (50.0f*L2E)   // fixed softmax shift, in log2 units

typedef __hip_bfloat16 bf16;
typedef unsigned short us;
typedef short bf16x8 __attribute__((ext_vector_type(8)));   // 8 bf16 = 4 VGPRs
typedef float f32x4  __attribute__((ext_vector_type(4)));
typedef unsigned short us4 __attribute__((ext_vector_type(4)));

// ---- workspace layout (floats) ----
#define O_XF   256
#define O_QB   (O_XF+1048576)      // QH (1048576 us) + QL (1048576 us) frag-major
#define O_KH   (O_QB+1048576)
#define O_KL   (O_KH+524288)
#define O_VT   (O_KL+524288)
#define O_XH   (O_VT+524288)       // x pre-split hi (1048576 us)
#define O_XL   (O_XH+524288)       // x pre-split lo
#define O_OP   (O_XL+524288)       // 2097152: key-split x2 partial O (fh aliases)
#define O_ML   (O_OP+2097152)      // 65536: key-split l (m is constant)
#define O_MASK (O_ML+65536)
#define O_B1   (O_MASK+4096)
#define O_B2   (O_B1+1024)
#define O_GM   (O_B2+512)
#define O_BT   (O_GM+4)
#define O_PREP (O_BT+4)
// conv segments: x | mask | b1 | b2 | gamma | beta (weights prep'd from raw inputs)
#define CONV_TOTAL (1048576+4096+1024+512+4+4)
#define CONV_BLOCKS ((CONV_TOTAL+255)/256)
#define PREP_BLOCKS 512
// prep region offsets in ushorts (relative to (us*)(ws+O_PREP))
#define PQH 0u
#define PQL 393216u
#define POH 786432u
#define POL 917504u
#define P1H 1048576u
#define P1L 1310720u
#define P2H 1572864u
#define P2L 1835008u

__device__ __forceinline__ float us2f(us u){
  unsigned int v = ((unsigned int)u) << 16; float f;
  __builtin_memcpy(&f, &v, 4); return f;
}
__device__ __forceinline__ us f2bf_rne(float f){
  unsigned int b = __float_as_uint(f);
  b += 0x7FFFu + ((b>>16)&1u);
  return (us)(b>>16);
}

#if __has_builtin(__builtin_amdgcn_exp2f)
#define EXP2F(x) __builtin_amdgcn_exp2f(x)
#else
#define EXP2F(x) exp2f(x)
#endif

#if __has_builtin(__builtin_amdgcn_cvt_pk_bf16_f32)
typedef __bf16 bf16x2_t __attribute__((ext_vector_type(2)));
__device__ __forceinline__ int pack_bf16(float a, float b){
  bf16x2_t r = __builtin_amdgcn_cvt_pk_bf16_f32(a, b);
  int i; __builtin_memcpy(&i, &r, 4); return i;
}
#else
__device__ __forceinline__ int pack_bf16(float a, float b){
  int b0 = __float_as_int(a) + 0x8000;
  int b1 = __float_as_int(b) + 0x8000;
  return (b1 & 0xFFFF0000) | ((int)((unsigned)b0 >> 16));
}
#endif

// Async global->LDS 16B copy (lane-linear layouts only).
__device__ __forceinline__ void gl_lds16(const us* g, us* l){
  __builtin_amdgcn_global_load_lds(
    (const __attribute__((address_space(1))) unsigned int*)g,
    (__attribute__((address_space(3))) unsigned int*)l, 16, 0, 0);
}

// x pre-split frag-major index for element (row, col), K=256 tiling.
__device__ __forceinline__ size_t xhl_idx(int row, int col){
  int rt = row>>6, rg = (row>>4)&3, L15 = row&15;
  int kc = col>>5, Q = (col>>3)&3, j = col&7;
  return ((size_t)(rt*8+kc))*2048 + rg*512 + Q*128 + L15*8 + j;
}

__device__ __forceinline__ float conv1(const void* src, size_t i, int flag){
  if(flag) return ((const float*)src)[i];
  return us2f(((const us*)src)[i]);
}

// Build fragment-major hi/lo bf16 B-operands reading RAW (flag-dtype) weights.
__device__ __forceinline__ void prep_b_raw(const void* W0, const void* W1v, const void* W2v,
                                           int baseoff, us* __restrict__ Bh, us* __restrict__ Bl,
                                           int Kd, int Nd, int qkv, int g, int flag)
{
  int total = (Kd/32)*(Nd/16)*64;
  if(g >= total) return;
  int lane = g & 63, fi = g >> 6;
  int ncN = Nd/16;
  int nc = fi % ncN, kc = fi / ncN;
  int Q = lane>>4, L15 = lane&15;
  int n = nc*16 + L15;
  const void* src;
  int off0, stride;
  if(qkv){
    int sec = n>>8, h = (n>>5)&7, kq = n&31;
    src = (sec==0)?W0:((sec==1)?W1v:W2v);
    off0 = baseoff + h*8192 + kq;
    stride = 32;
  } else {
    src = W0;
    off0 = baseoff + n;
    stride = Nd;
  }
  #pragma unroll
  for(int j=0;j<8;j++){
    int k = kc*32 + Q*8 + j;
    float v = conv1(src, (size_t)off0 + (size_t)k*stride, flag);
    us hb = f2bf_rne(v);
    Bh[(size_t)g*8 + j] = hb;
    Bl[(size_t)g*8 + j] = f2bf_rne(v - us2f(hb));
  }
}

// Fused: dtype-detect (per-block) + weight prep (blocks 0..511) + input conversion.
__global__ void conv_prep(const void* s0, const void* s1, const void* sWq, const void* sWk,
                          const void* sWv, const void* sWo, const void* sW1, const void* sb1,
                          const void* sW2, const void* sb2, const void* sgm, const void* sbt,
                          float* __restrict__ ws, int* __restrict__ flagp)
{
  __shared__ int fsh[4];
  int bad = 0;
  const us* xr = (const us*)s0;
  for(int i=threadIdx.x; i<4096; i+=256){
    float f = us2f(xr[i]);
    if(!(fabsf(f) < 1e3f)) bad = 1;
  }
  unsigned long long m = __ballot(bad);
  if((threadIdx.x&63)==0) fsh[threadIdx.x>>6] = (m!=0ull);
  __syncthreads();
  int flag = (fsh[0]|fsh[1]|fsh[2]|fsh[3]);
  if(blockIdx.x==0 && threadIdx.x==0) *flagp = flag;

  int b = blockIdx.x;
  if(b < PREP_BLOCKS){
    int layer = b >> 8, lb = b & 255;
    us* prep = (us*)(ws + O_PREP);
    if(lb < 96){
      int g = lb*256 + threadIdx.x;
      prep_b_raw(sWq, sWk, sWv, layer*65536, prep+PQH+(size_t)layer*196608,
                 prep+PQL+(size_t)layer*196608, 256, 768, 1, g, flag);
    } else if(lb < 128){
      int g = (lb-96)*256 + threadIdx.x;
      prep_b_raw(sWo, nullptr, nullptr, layer*65536, prep+POH+(size_t)layer*65536,
                 prep+POL+(size_t)layer*65536, 256, 256, 0, g, flag);
    } else if(lb < 192){
      int g = (lb-128)*256 + threadIdx.x;
      prep_b_raw(sW1, nullptr, nullptr, layer*131072, prep+P1H+(size_t)layer*131072,
                 prep+P1L+(size_t)layer*131072, 256, 512, 0, g, flag);
    } else {
      int g = (lb-192)*256 + threadIdx.x;
      prep_b_raw(sW2, nullptr, nullptr, layer*131072, prep+P2H+(size_t)layer*131072,
                 prep+P2L+(size_t)layer*131072, 512, 256, 0, g, flag);
    }
    return;
  }
  int g = (b - PREP_BLOCKS)*256 + threadIdx.x;
  if(g < 1048576){
    float v = conv1(s0, g, flag);
    ws[O_XF+g] = v;
    us hb = f2bf_rne(v);
    us lb = f2bf_rne(v - us2f(hb));
    size_t xi = xhl_idx(g>>8, g&255);
    ((us*)(ws+O_XH))[xi] = hb;
    ((us*)(ws+O_XL))[xi] = lb;
    return;
  }
  g -= 1048576;
  if(g < 4096){ ws[O_MASK+g] = conv1(s1, g, flag)*L2E; return; }
  g -= 4096;
  if(g < 1024){ ws[O_B1+g] = conv1(sb1, g, flag); return; }
  g -= 1024;
  if(g < 512){ ws[O_B2+g] = conv1(sb2, g, flag); return; }
  g -= 512;
  if(g < 4){ ws[O_GM+g] = conv1(sgm, g, flag); return; }
  g -= 4;
  if(g < 4){ ws[O_BT+g] = conv1(sbt, g, flag); return; }
}

// Split-bf16 MFMA GEMM (64x64 tile, 4 waves, 3 MFMAs/frag/K32), A pre-split.
// MODE 0: QKV -> QH/QL, KH/KL, VT frag-major via LDS-transposed COALESCED stores.
// MODE 2: relu(acc+bias) -> O (fp32, coalesced).
template<int MODE>
__launch_bounds__(256)
__global__ void gemm_mfma(const us* __restrict__ Axh, const us* __restrict__ Axl,
                          const us* __restrict__ Bh, const us* __restrict__ Bl,
                          const float* __restrict__ bias,
                          float* __restrict__ O,
                          us* __restrict__ QH, us* __restrict__ QL,
                          us* __restrict__ KH, us* __restrict__ KL, us* __restrict__ VT,
                          int Ncols, int Kdim)
{
  __shared__ __align__(16) us SH[9216];   // K-loop: Ah|Al|Bhs|Bls (4x2048); epi: TH(4608)|TL(4608)
  us* Ah = SH; us* Al = SH+2048; us* Bhs = SH+4096; us* Bls = SH+6144;
  const int t = threadIdx.x;
  const int w = t>>6, lane = t&63;
  const int Q = lane>>4, L15 = lane&15;
  const int row0 = blockIdx.x*64;
  const int nc0 = blockIdx.y*4;
  const int col0 = blockIdx.y*64;

  f32x4 acc[2][2];
  #pragma unroll
  for(int i=0;i<2;i++)
    #pragma unroll
    for(int j=0;j<2;j++) acc[i][j] = (f32x4){0.f,0.f,0.f,0.f};

  const int nKc = Kdim>>5;
  const int ncW = Ncols>>4;

  for(int kc=0; kc<nKc; kc++){
    {
      size_t abase = ((size_t)(blockIdx.x*nKc + kc))*2048;
      gl_lds16(&Axh[abase + (size_t)t*8], &Ah[t*8]);
      gl_lds16(&Axl[abase + (size_t)t*8], &Al[t*8]);
      size_t gidx = ((size_t)(kc*ncW + nc0 + w)*64 + lane)*8;
      gl_lds16(&Bh[gidx], &Bhs[t*8]);
      gl_lds16(&Bl[gidx], &Bls[t*8]);
    }
    __syncthreads();

    bf16x8 aAh[2], aAl[2], bBh[2], bBl[2];
    #pragma unroll
    for(int rg2=0;rg2<2;rg2++){
      int rg = (w&1)*2 + rg2;
      aAh[rg2] = *(const bf16x8*)&Ah[rg*512 + lane*8];
      aAl[rg2] = *(const bf16x8*)&Al[rg*512 + lane*8];
    }
    #pragma unroll
    for(int cg2=0;cg2<2;cg2++){
      int nc = (w>>1)*2 + cg2;
      bBh[cg2] = *(const bf16x8*)&Bhs[nc*512 + lane*8];
      bBl[cg2] = *(const bf16x8*)&Bls[nc*512 + lane*8];
    }
    #pragma unroll
    for(int rg2=0;rg2<2;rg2++)
      #pragma unroll
      for(int cg2=0;cg2<2;cg2++){
        acc[rg2][cg2] = __builtin_amdgcn_mfma_f32_16x16x32_bf16(aAl[rg2], bBh[cg2], acc[rg2][cg2], 0,0,0);
        acc[rg2][cg2] = __builtin_amdgcn_mfma_f32_16x16x32_bf16(aAh[rg2], bBl[cg2], acc[rg2][cg2], 0,0,0);
        acc[rg2][cg2] = __builtin_amdgcn_mfma_f32_16x16x32_bf16(aAh[rg2], bBh[cg2], acc[rg2][cg2], 0,0,0);
      }
    __syncthreads();
  }

  if(MODE==0){
    us* TH = SH;          // 64*72 = 4608 us
    us* TL = SH + 4608;
    #pragma unroll
    for(int rg2=0;rg2<2;rg2++)
      #pragma unroll
      for(int cg2=0;cg2<2;cg2++)
        #pragma unroll
        for(int r=0;r<4;r++){
          int rl = (w&1)*32 + rg2*16 + Q*4 + r;
          int cl = (w>>1)*32 + cg2*16 + L15;
          float va = acc[rg2][cg2][r];
          us hb = f2bf_rne(va);
          TH[rl*72+cl] = hb;
          TL[rl*72+cl] = f2bf_rne(va - us2f(hb));
        }
    __syncthreads();
    const int sec = col0>>8;
    const int h0  = (col0&255)>>5;
    const int b_  = row0>>11;
    const int srow0 = row0 & 2047;
    if(sec < 2){
      us* DH = (sec==0) ? QH : KH;
      us* DL = (sec==0) ? QL : KL;
      #pragma unroll
      for(int u2=0; u2<2; u2++){
        int u = w + u2*4;
        int rg = u&3, half = u>>2;
        int lbase = (rg*16 + L15)*72 + half*32 + Q*8;
        bf16x8 hv = *(const bf16x8*)&TH[lbase];
        bf16x8 lv = *(const bf16x8*)&TL[lbase];
        int bh = b_*NH + h0 + half;
        size_t dbase = ((size_t)(bh*128 + (srow0>>4) + rg)*64 + lane)*8;
        *(bf16x8*)&DH[dbase] = hv;
        *(bf16x8*)&DL[dbase] = lv;
      }
    } else {
      #pragma unroll
      for(int u2=0; u2<2; u2++){
        int u = w + u2*4;
        int sgrp = u&1, kqh = (u>>1)&1, half = u>>2;
        union{ us u8[8]; bf16x8 v; } vv;
        #pragma unroll
        for(int j=0;j<8;j++){
          int rl = sgrp*32 + Q*8 + j;
          int cl = half*32 + kqh*16 + L15;
          vv.u8[j] = TH[rl*72+cl];
        }
        int bh = b_*NH + h0 + half;
        size_t dbase = ((size_t)((bh*64 + (srow0>>5) + sgrp)*2 + kqh)*64 + lane)*8;
        *(bf16x8*)&VT[dbase] = vv.v;
      }
    }
  } else {
    #pragma unroll
    for(int rg2=0;rg2<2;rg2++)
      #pragma unroll
      for(int cg2=0;cg2<2;cg2++)
        #pragma unroll
        for(int r=0;r<4;r++){
          int row = row0 + (w&1)*32 + rg2*16 + Q*4 + r;
          int c   = col0 + (w>>1)*32 + cg2*16 + L15;
          float v = acc[rg2][cg2][r] + bias[c];
          O[(size_t)row*Ncols + c] = v>0.f ? v : 0.f;
        }
  }
}

// Fused narrow-N GEMM + residual (+bias) + LayerNorm, N=256 (unchanged).
template<int SRC>
__launch_bounds__(256)
__global__ void gemm_ln(const float* __restrict__ A,
                        const float* __restrict__ OpartA, const float* __restrict__ MLA,
                        const us* __restrict__ Bh, const us* __restrict__ Bl,
                        const float* __restrict__ bias, const float* __restrict__ res,
                        float* __restrict__ xf,
                        us* __restrict__ xh, us* __restrict__ xl,
                        const float* __restrict__ gamma, const float* __restrict__ beta, int gi,
                        void* __restrict__ out, int write_out,
                        const int* __restrict__ flagp, int Kdim)
{
  __shared__ __align__(16) us Ah[512], Al[512];
  __shared__ __align__(16) us Bhs[8192], Bls[8192];
  __shared__ float lred[128];
  const int t = threadIdx.x;
  const int w = t>>6, lane = t&63;
  const int Q = lane>>4, L15 = lane&15;
  const int row0 = blockIdx.x*16;
  const int nKc = Kdim>>5;

  f32x4 acc[4];
  #pragma unroll
  for(int cg=0;cg<4;cg++) acc[cg] = (f32x4){0.f,0.f,0.f,0.f};

  for(int kc=0; kc<nKc; kc++){
    if(t < 128){
      int r = t>>3;
      int kl = (t&7)*4;
      float4 v;
      if(SRC==0){
        int row = row0 + r;
        int b_ = row>>11, s_ = row&2047;
        size_t i0 = (size_t)(b_*8 + kc)*2048 + s_;    // h == kc (Kdim=256)
        float l = MLA[i0] + MLA[i0+32768];
        float inv = 1.f/l;
        float4 o0 = *(const float4*)&OpartA[i0*32 + kl];
        float4 o1 = *(const float4*)&OpartA[(i0+32768)*32 + kl];
        v.x=(o0.x+o1.x)*inv; v.y=(o0.y+o1.y)*inv;
        v.z=(o0.z+o1.z)*inv; v.w=(o0.w+o1.w)*inv;
      } else {
        v = *(const float4*)&A[(size_t)(row0+r)*Kdim + kc*32 + kl];
      }
      float f[4] = {v.x, v.y, v.z, v.w};
      us4 h4, l4;
      #pragma unroll
      for(int j=0;j<4;j++){
        us hb = f2bf_rne(f[j]);
        h4[j] = hb; l4[j] = f2bf_rne(f[j] - us2f(hb));
      }
      int off = (kl>>3)*128 + r*8 + (kl&7);
      *(us4*)&Ah[off] = h4;
      *(us4*)&Al[off] = l4;
    }
    #pragma unroll
    for(int ii=0; ii<4; ii++){
      int unit = w + ii*4;
      size_t gidx = ((size_t)(kc*16 + unit)*64 + lane)*8;
      gl_lds16(&Bh[gidx], &Bhs[unit*512 + lane*8]);
      gl_lds16(&Bl[gidx], &Bls[unit*512 + lane*8]);
    }
    __syncthreads();

    bf16x8 aAh = *(const bf16x8*)&Ah[lane*8];
    bf16x8 aAl = *(const bf16x8*)&Al[lane*8];
    #pragma unroll
    for(int cg=0;cg<4;cg++){
      int unit = w*4 + cg;
      bf16x8 bBh = *(const bf16x8*)&Bhs[unit*512 + lane*8];
      bf16x8 bBl = *(const bf16x8*)&Bls[unit*512 + lane*8];
      acc[cg] = __builtin_amdgcn_mfma_f32_16x16x32_bf16(aAl, bBh, acc[cg], 0,0,0);
      acc[cg] = __builtin_amdgcn_mfma_f32_16x16x32_bf16(aAh, bBl, acc[cg], 0,0,0);
      acc[cg] = __builtin_amdgcn_mfma_f32_16x16x32_bf16(aAh, bBh, acc[cg], 0,0,0);
    }
    __syncthreads();
  }

  float tmp[4][4];
  #pragma unroll
  for(int cg=0;cg<4;cg++)
    #pragma unroll
    for(int r=0;r<4;r++){
      int row = row0 + Q*4 + r;
      int c = w*64 + cg*16 + L15;
      float v = acc[cg][r] + res[(size_t)row*DD + c];
      if(SRC==1) v += bias[c];
      tmp[cg][r] = v;
    }
  float s[4], sq[4];
  #pragma unroll
  for(int r=0;r<4;r++){
    s[r]  = tmp[0][r]+tmp[1][r]+tmp[2][r]+tmp[3][r];
    sq[r] = tmp[0][r]*tmp[0][r]+tmp[1][r]*tmp[1][r]+tmp[2][r]*tmp[2][r]+tmp[3][r]*tmp[3][r];
  }
  #pragma unroll
  for(int off=1; off<16; off<<=1)
    #pragma unroll
    for(int r=0;r<4;r++){
      s[r]  += __shfl_xor(s[r], off);
      sq[r] += __shfl_xor(sq[r], off);
    }
  if(L15==0){
    #pragma unroll
    for(int r=0;r<4;r++){
      int rl = Q*4 + r;
      lred[(w*16 + rl)*2]   = s[r];
      lred[(w*16 + rl)*2+1] = sq[r];
    }
  }
  __syncthreads();
  float g = gamma[gi], bb = beta[gi];
  float scv[4], mnv[4];
  #pragma unroll
  for(int r=0;r<4;r++){
    int rl = Q*4 + r;
    float S  = lred[rl*2]   + lred[(16+rl)*2]   + lred[(32+rl)*2]   + lred[(48+rl)*2];
    float SQ = lred[rl*2+1] + lred[(16+rl)*2+1] + lred[(32+rl)*2+1] + lred[(48+rl)*2+1];
    float mean = S*(1.f/DD);
    float var  = SQ*(1.f/DD) - mean*mean;
    scv[r] = rsqrtf(var+LN_EPS)*g;
    mnv[r] = mean;
  }
  int flag = write_out ? *flagp : 0;
  #pragma unroll
  for(int cg=0;cg<4;cg++)
    #pragma unroll
    for(int r=0;r<4;r++){
      int row = row0 + Q*4 + r;
      int c = w*64 + cg*16 + L15;
      float val = (tmp[cg][r]-mnv[r])*scv[r] + bb;
      xf[(size_t)row*DD + c] = val;
      us hb = f2bf_rne(val);
      size_t xi = xhl_idx(row, c);
      xh[xi] = hb;
      xl[xi] = f2bf_rne(val - us2f(hb));
      if(write_out){
        if(flag) ((float*)out)[(size_t)row*DD + c] = val;
        else     ((bf16*)out)[(size_t)row*DD + c] = __float2bfloat16(val);
      }
    }
}

// MFMA flash attention v8: software-pipelined KT=64 double-buffer.
// Per stage: barrier -> issue async loads(s+1) into other buffer -> compute(s).
// The vmcnt(0) drain at each barrier now covers loads issued a full compute
// stage earlier — staging latency leaves the critical path.
__launch_bounds__(256)
__global__ void attn_kernel(const us* __restrict__ QH, const us* __restrict__ QL,
                            const us* __restrict__ KH, const us* __restrict__ KL,
                            const us* __restrict__ VT,
                            const float* __restrict__ mask,
                            float* __restrict__ Opart, float* __restrict__ ML)
{
  __shared__ __align__(16) us Khs[4096], Kls[4096], Vts[4096];  // 2 bufs x 2048
  __shared__ __align__(16) float Msl[128];                       // 2 bufs x 64
  const int t = threadIdx.x;
  const int bh = blockIdx.x >> 6;
  const int qt = (blockIdx.x & 63) >> 1;
  const int ks = blockIdx.x & 1;
  const int b_ = bh >> 3;
  const int wv = t >> 6;
  const int lane = t & 63;
  const int Q = lane >> 4, L15 = lane & 15;
  const int q0 = qt*64 + wv*16;

  size_t qidx = ((size_t)(bh*128 + qt*4 + wv)*64 + lane)*8;
  const bf16x8 qh_v = *(const bf16x8*)&QH[qidx];
  const bf16x8 ql_v = *(const bf16x8*)&QL[qidx];

  const us* KHbh = KH + (size_t)bh*65536;
  const us* KLbh = KL + (size_t)bh*65536;
  const us* VTbh = VT + (size_t)bh*65536;
  const int base = ks*1024;

  f32x4 Oa0a = {0.f,0.f,0.f,0.f}, Oa0b = {0.f,0.f,0.f,0.f};
  f32x4 Oa1a = {0.f,0.f,0.f,0.f}, Oa1b = {0.f,0.f,0.f,0.f};
  float lacc = 0.f;

  // prologue: stage 0 into buffer 0
  {
    size_t kbase = (size_t)(base>>4)*512;
    size_t vbase = (size_t)(base>>5)*1024;
    gl_lds16(&KHbh[kbase + (size_t)t*8], &Khs[t*8]);
    gl_lds16(&KLbh[kbase + (size_t)t*8], &Kls[t*8]);
    gl_lds16(&VTbh[vbase + (size_t)t*8], &Vts[t*8]);
    if(t < 64) Msl[t] = mask[b_*SS + base + t];
  }

  for(int s=0; s<16; s++){
    __syncthreads();                         // drains loads(s); orders buffer reuse
    if(s < 15){
      int t0n = base + (s+1)*64;
      int bn = (s+1)&1;
      size_t kbase = (size_t)(t0n>>4)*512;
      size_t vbase = (size_t)(t0n>>5)*1024;
      gl_lds16(&KHbh[kbase + (size_t)t*8], &Khs[bn*2048 + t*8]);
      gl_lds16(&KLbh[kbase + (size_t)t*8], &Kls[bn*2048 + t*8]);
      gl_lds16(&VTbh[vbase + (size_t)t*8], &Vts[bn*2048 + t*8]);
      if(t < 64) Msl[bn*64 + t] = mask[b_*SS + t0n + t];
    }
    const int bo = (s&1)*2048;
    const int mo = (s&1)*64;

    // QK^T -> S^T (3 MFMAs per 16-key tile, 4 tiles)
    f32x4 St[4];
    const f32x4 zz = {0.f,0.f,0.f,0.f};
    #pragma unroll
    for(int kt=0;kt<4;kt++){
      bf16x8 aKh = *(const bf16x8*)&Khs[bo + kt*512 + lane*8];
      bf16x8 aKl = *(const bf16x8*)&Kls[bo + kt*512 + lane*8];
      f32x4 a = __builtin_amdgcn_mfma_f32_16x16x32_bf16(aKl, qh_v, zz, 0,0,0);
      a = __builtin_amdgcn_mfma_f32_16x16x32_bf16(aKh, ql_v, a, 0,0,0);
      a = __builtin_amdgcn_mfma_f32_16x16x32_bf16(aKh, qh_v, a, 0,0,0);
      St[kt] = a;
    }

    // fixed-shift softmax in log2 space
    float lsum = 0.f;
    #pragma unroll
    for(int kt=0;kt<4;kt++){
      float4 mv = *(const float4*)&Msl[mo + kt*16 + Q*4];
      float mvr[4] = {mv.x, mv.y, mv.z, mv.w};
      #pragma unroll
      for(int r=0;r<4;r++){
        float p = EXP2F(fmaf(mvr[r], St[kt][r], -SOFT_SHIFT_L2E));
        St[kt][r] = p;
        lsum += p;
      }
    }
    lacc += lsum;

    // pack P -> bf16 pairs
    int pk[4][2];
    #pragma unroll
    for(int kt=0;kt<4;kt++){
      pk[kt][0] = pack_bf16(St[kt][0], St[kt][1]);
      pk[kt][1] = pack_bf16(St[kt][2], St[kt][3]);
    }

    // PV: O^T += V^T · P^T (2 chunks of 32 keys; c0 -> a regs, c1 -> b regs)
    #pragma unroll
    for(int c=0;c<2;c++){
      union { int i[4]; bf16x8 v; } bu;
      #pragma unroll
      for(int d=0;d<4;d++){
        int srcl = (((Q&1)*2 + (d>>1))<<4) | L15;
        int vlo = __shfl(pk[2*c  ][d&1], srcl, 64);
        int vhi = __shfl(pk[2*c+1][d&1], srcl, 64);
        bu.i[d] = (Q & 2) ? vhi : vlo;
      }
      bf16x8 aV0 = *(const bf16x8*)&Vts[bo + (c*2+0)*512 + lane*8];
      bf16x8 aV1 = *(const bf16x8*)&Vts[bo + (c*2+1)*512 + lane*8];
      if(c == 0){
        Oa0a = __builtin_amdgcn_mfma_f32_16x16x32_bf16(aV0, bu.v, Oa0a, 0,0,0);
        Oa1a = __builtin_amdgcn_mfma_f32_16x16x32_bf16(aV1, bu.v, Oa1a, 0,0,0);
      } else {
        Oa0b = __builtin_amdgcn_mfma_f32_16x16x32_bf16(aV0, bu.v, Oa0b, 0,0,0);
        Oa1b = __builtin_amdgcn_mfma_f32_16x16x32_bf16(aV1, bu.v, Oa1b, 0,0,0);
      }
    }
  }

  f32x4 Oa0 = Oa0a + Oa0b;
  f32x4 Oa1 = Oa1a + Oa1b;
  lacc += __shfl_xor(lacc, 16);
  lacc += __shfl_xor(lacc, 32);

  float* opp = &Opart[((size_t)(ks*16+bh)*SS + q0 + L15)*32];
  #pragma unroll
  for(int r=0;r<4;r++){
    opp[Q*4+r]    = Oa0[r];
    opp[16+Q*4+r] = Oa1[r];
  }
  if(Q==0){
    ML[(size_t)(ks*16+bh)*SS + q0 + L15] = lacc;
  }
}

extern "C" void kernel_launch(void* const* d_in, const int* in_sizes, int n_in,
                              void* d_out, int out_size, void* d_ws, size_t ws_size,
                              hipStream_t stream)
{
  float* ws = (float*)d_ws;
  int* flagp = (int*)d_ws;

  float* xf  = ws + O_XF;
  us* QHb = (us*)(ws + O_QB);
  us* QLb = QHb + 1048576;
  us* KH = (us*)(ws + O_KH);
  us* KL = (us*)(ws + O_KL);
  us* VT = (us*)(ws + O_VT);
  us* XH = (us*)(ws + O_XH);
  us* XL = (us*)(ws + O_XL);
  float* Opart = ws + O_OP;
  float* ML  = ws + O_ML;
  float* fh  = Opart;                   // FFN hidden aliases Opart (dead after Wo-fused)
  float* b1f = ws + O_B1;
  float* b2f_ = ws + O_B2;
  float* gmf = ws + O_GM;
  float* btf = ws + O_BT;
  us* prep = (us*)(ws + O_PREP);

  conv_prep<<<PREP_BLOCKS+CONV_BLOCKS,256,0,stream>>>(
      d_in[0], d_in[1], d_in[2], d_in[3], d_in[4], d_in[5],
      d_in[6], d_in[7], d_in[8], d_in[9], d_in[10], d_in[11],
      ws, flagp);

  for(int i=0;i<NL;i++){
    const float* b1i = b1f + (size_t)i*DFF;
    const float* b2i = b2f_ + (size_t)i*DD;

    dim3 g0(64, 12);
    gemm_mfma<0><<<g0,256,0,stream>>>(XH, XL,
                                      prep+PQH+(size_t)i*196608, prep+PQL+(size_t)i*196608,
                                      nullptr, nullptr,
                                      QHb, QLb, KH, KL, VT, 768, 256);
    attn_kernel<<<1024,256,0,stream>>>(QHb, QLb, KH, KL, VT, ws + O_MASK, Opart, ML);
    gemm_ln<0><<<256,256,0,stream>>>(nullptr, Opart, ML,
                                     prep+POH+(size_t)i*65536, prep+POL+(size_t)i*65536,
                                     nullptr, xf, xf, XH, XL,
                                     gmf, btf, 2*i, d_out, 0, flagp, 256);
    dim3 g2(64, 8);
    gemm_mfma<2><<<g2,256,0,stream>>>(XH, XL,
                                      prep+P1H+(size_t)i*131072, prep+P1L+(size_t)i*131072,
                                      b1i, fh,
                                      nullptr, nullptr, nullptr, nullptr, nullptr, 512, 256);
    gemm_ln<1><<<256,256,0,stream>>>(fh, nullptr, nullptr,
                                     prep+P2H+(size_t)i*131072, prep+P2L+(size_t)i*131072,
                                     b2i, xf, xf, XH, XL,
                                     gmf, btf, 2*i+1, d_out, (i==NL-1)?1:0, flagp, 512);
  }
}